// Round 1
// baseline (7490.671 us; speedup 1.0000x reference)
//
#include <hip/hip_runtime.h>
#include <math.h>

#define CDIM 384
#define SDIM 4096
#define BDIM 4
#define DINC 768
#define NST  16

// ---------------------------------------------------------------------------
// Weight transpose for direct conv: W[co][ci][27] -> Wt[ci*27][co]
// so the 8 per-tap output-channel weights are contiguous & wave-uniform.
// ---------------------------------------------------------------------------
__global__ __launch_bounds__(256)
void transpose_w_kernel(const float* __restrict__ W, float* __restrict__ Wt) {
    int idx = blockIdx.x * 256 + threadIdx.x;            // 384*384*27
    if (idx >= CDIM * CDIM * 27) return;
    int co = idx % CDIM;
    int rest = idx / CDIM;                               // ci*27 + tap
    int tap = rest % 27;
    int ci = rest / 27;
    Wt[idx] = W[((size_t)co * CDIM + ci) * 27 + tap];
}

// ---------------------------------------------------------------------------
// Direct 3x3x3 conv, pad=1. grid = (d=16, co/8=48, b=4), block=256 (one
// 16x16 hw-plane). Each thread: 8 output channels in registers. Weights are
// uniform (s_load) from Wt; input rows hit L1 (plane = 1KB, reused 27x).
// Conv bias skipped: it cancels exactly through the following InstanceNorm.
// ---------------------------------------------------------------------------
__global__ __launch_bounds__(256)
void conv3x3_kernel(const float* __restrict__ X, const float* __restrict__ Wt,
                    float* __restrict__ Y) {
    const int d = blockIdx.x;
    const int cog = blockIdx.y;
    const int b = blockIdx.z;
    const int t = threadIdx.x;
    const int h = t >> 4, w = t & 15;

    float acc[8];
#pragma unroll
    for (int j = 0; j < 8; ++j) acc[j] = 0.f;

    const float* xb = X + (size_t)b * CDIM * SDIM;
    const int wbase = cog * 8;

    for (int ci = 0; ci < CDIM; ++ci) {
        const float* xc = xb + (size_t)ci * SDIM;
        const float* wr = Wt + (size_t)(ci * 27) * CDIM + wbase;
#pragma unroll
        for (int kd = 0; kd < 3; ++kd) {
            const int dd = d + kd - 1;
            if (dd < 0 || dd > 15) continue;             // uniform branch
#pragma unroll
            for (int kh = 0; kh < 3; ++kh) {
                const int hh = h + kh - 1;
                const bool okh = (hh >= 0) && (hh < 16);
#pragma unroll
                for (int kw = 0; kw < 3; ++kw) {
                    const int ww = w + kw - 1;
                    const bool ok = okh && (ww >= 0) && (ww < 16);
                    const float xv = ok ? xc[dd * 256 + hh * 16 + ww] : 0.f;
                    const float* wv = wr + (kd * 9 + kh * 3 + kw) * CDIM;
#pragma unroll
                    for (int j = 0; j < 8; ++j)
                        acc[j] = fmaf(xv, wv[j], acc[j]);
                }
            }
        }
    }
    float* yb = Y + ((size_t)b * CDIM + wbase) * SDIM + d * 256 + t;
#pragma unroll
    for (int j = 0; j < 8; ++j) yb[(size_t)j * SDIM] = acc[j];
}

// ---------------------------------------------------------------------------
// InstanceNorm stats: one block per (b,c); mean + rsqrt(var+eps) (biased var).
// ---------------------------------------------------------------------------
__global__ __launch_bounds__(256)
void inorm_stats_kernel(const float* __restrict__ X, float* __restrict__ stats) {
    const int bc = blockIdx.x;                           // B*C = 1536
    const float* xp = X + (size_t)bc * SDIM;
    float s = 0.f, ss = 0.f;
    for (int i = threadIdx.x * 4; i < SDIM; i += 1024) {
        float4 v = *(const float4*)(xp + i);
        s += v.x + v.y + v.z + v.w;
        ss += v.x * v.x + v.y * v.y + v.z * v.z + v.w * v.w;
    }
#pragma unroll
    for (int off = 32; off > 0; off >>= 1) {
        s += __shfl_down(s, off);
        ss += __shfl_down(ss, off);
    }
    __shared__ float rs[4], rss[4];
    const int wid = threadIdx.x >> 6;
    if ((threadIdx.x & 63) == 0) { rs[wid] = s; rss[wid] = ss; }
    __syncthreads();
    if (threadIdx.x == 0) {
        float S = rs[0] + rs[1] + rs[2] + rs[3];
        float SS = rss[0] + rss[1] + rss[2] + rss[3];
        float m = S * (1.f / SDIM);
        float var = SS * (1.f / SDIM) - m * m;
        stats[bc * 2] = m;
        stats[bc * 2 + 1] = rsqrtf(var + 1e-5f);
    }
}

// ---------------------------------------------------------------------------
// y = relu((x-m)*rstd) [+ res]  — elementwise float4; Out may alias X.
// ---------------------------------------------------------------------------
__global__ __launch_bounds__(256)
void norm_relu_kernel(const float* __restrict__ X, const float* __restrict__ stats,
                      const float* __restrict__ Res, float* __restrict__ Out) {
    const size_t idx = (size_t)blockIdx.x * 256 + threadIdx.x;
    const size_t i4 = idx * 4;
    const int bc = (int)(i4 >> 12);
    const float m = stats[bc * 2], r = stats[bc * 2 + 1];
    float4 v = *(const float4*)(X + i4);
    float4 o;
    o.x = fmaxf((v.x - m) * r, 0.f);
    o.y = fmaxf((v.y - m) * r, 0.f);
    o.z = fmaxf((v.z - m) * r, 0.f);
    o.w = fmaxf((v.w - m) * r, 0.f);
    if (Res) {
        float4 q = *(const float4*)(Res + i4);
        o.x += q.x; o.y += q.y; o.z += q.z; o.w += q.w;
    }
    *(float4*)(Out + i4) = o;
}

// ---------------------------------------------------------------------------
// LayerNorm over C with transpose: xg [b][c][s] -> tn [b][l][c].
// One wave per token; lane handles 6 channels (strided reads, coalesced writes).
// ---------------------------------------------------------------------------
__global__ __launch_bounds__(256)
void layernorm_kernel(const float* __restrict__ Xg, const float* __restrict__ gam,
                      const float* __restrict__ bet, float* __restrict__ Tn) {
    const int token = blockIdx.x * 4 + (threadIdx.x >> 6);
    const int lane = threadIdx.x & 63;
    const int b = token >> 12, l = token & 4095;
    const float* xp = Xg + (size_t)b * CDIM * SDIM + l;
    float v[6];
    float s = 0.f, ss = 0.f;
#pragma unroll
    for (int i = 0; i < 6; ++i) {
        v[i] = xp[(size_t)(lane + i * 64) * SDIM];
        s += v[i]; ss += v[i] * v[i];
    }
#pragma unroll
    for (int off = 32; off > 0; off >>= 1) {
        s += __shfl_down(s, off);
        ss += __shfl_down(ss, off);
    }
    s = __shfl(s, 0); ss = __shfl(ss, 0);
    const float m = s * (1.f / CDIM);
    const float r = rsqrtf(ss * (1.f / CDIM) - m * m + 1e-5f);
    float* tp = Tn + (size_t)token * CDIM;
#pragma unroll
    for (int i = 0; i < 6; ++i) {
        const int c = lane + i * 64;
        tp[c] = (v[i] - m) * r * gam[c] + bet[c];
    }
}

// ---------------------------------------------------------------------------
// Tiled fp32 GEMM. C[M,N] = A[M,K] (row-major, lda) x B.
//   NT=false: B[K,N] row-major (ldb).  NT=true: B[N,K] row-major (ldb).
// Tile 128x64xBK16, 256 threads, 8x4 per-thread microtile.
// EPI: 0 plain store; 1 split xz -> C=X1/C2=X2 (DIN=768 halves);
//      2 +bias[n], softplus; 3 transposed store to [b][n][l] (out tensor).
// M must be a multiple of 128 (holds for 384 and 16384). N,K masked.
// ---------------------------------------------------------------------------
template<bool NT, int EPI>
__global__ __launch_bounds__(256)
void gemm_kernel(const float* __restrict__ A, const float* __restrict__ B,
                 float* __restrict__ C, float* __restrict__ C2,
                 const float* __restrict__ bias,
                 int M, int N, int K, int lda, int ldb, int ldc,
                 long sA, long sB, long sC) {
    __shared__ __align__(16) float As[16][132];   // +4 pad: keeps 16B align, <=2-way banks
    __shared__ __align__(16) float Bs[16][68];
    const int t = threadIdx.x;
    const int m0 = blockIdx.y * 128;
    const int n0 = blockIdx.x * 64;
    A += (long)blockIdx.z * sA;
    B += (long)blockIdx.z * sB;
    C += (long)blockIdx.z * sC;

    float acc[8][4];
#pragma unroll
    for (int i = 0; i < 8; ++i)
#pragma unroll
        for (int j = 0; j < 4; ++j) acc[i][j] = 0.f;

    const int mr = (t & 15) * 8;
    const int nr = (t >> 4) * 4;

    for (int k0 = 0; k0 < K; k0 += 16) {
#pragma unroll
        for (int idx = 0; idx < 8; ++idx) {              // stage A 128x16
            const int e = idx * 256 + t;
            const int k = e & 15, m = e >> 4;
            float v = 0.f;
            if (k0 + k < K) v = A[(size_t)(m0 + m) * lda + (k0 + k)];
            As[k][m] = v;
        }
#pragma unroll
        for (int idx = 0; idx < 4; ++idx) {              // stage B 16x64
            const int e = idx * 256 + t;
            if (NT) {
                const int k = e & 15, n = e >> 4;
                float v = 0.f;
                if ((n0 + n) < N && (k0 + k) < K) v = B[(size_t)(n0 + n) * ldb + (k0 + k)];
                Bs[k][n] = v;
            } else {
                const int n = e & 63, k = e >> 6;
                float v = 0.f;
                if ((n0 + n) < N && (k0 + k) < K) v = B[(size_t)(k0 + k) * ldb + (n0 + n)];
                Bs[k][n] = v;
            }
        }
        __syncthreads();
#pragma unroll
        for (int k = 0; k < 16; ++k) {
            float4 a0 = *(const float4*)&As[k][mr];
            float4 a1 = *(const float4*)&As[k][mr + 4];
            float4 b0 = *(const float4*)&Bs[k][nr];
            const float av[8] = {a0.x, a0.y, a0.z, a0.w, a1.x, a1.y, a1.z, a1.w};
            const float bv[4] = {b0.x, b0.y, b0.z, b0.w};
#pragma unroll
            for (int i = 0; i < 8; ++i)
#pragma unroll
                for (int j = 0; j < 4; ++j)
                    acc[i][j] = fmaf(av[i], bv[j], acc[i][j]);
        }
        __syncthreads();
    }

#pragma unroll
    for (int i = 0; i < 8; ++i) {
        const int m = m0 + mr + i;
#pragma unroll
        for (int j = 0; j < 4; ++j) {
            const int n = n0 + nr + j;
            if (n >= N) continue;
            float v = acc[i][j];
            if (EPI == 0) {
                C[(size_t)m * ldc + n] = v;
            } else if (EPI == 1) {                       // split xin | z
                if (n < DINC) C[(size_t)m * DINC + n] = v;
                else          C2[(size_t)m * DINC + (n - DINC)] = v;
            } else if (EPI == 2) {                       // bias + softplus
                v += bias[n];
                v = (v > 20.f) ? v : log1pf(__expf(v));
                C[(size_t)m * ldc + n] = v;
            } else {                                     // transposed out store
                const int bb = m >> 12, l = m & 4095;
                C[((size_t)bb * CDIM + n) * SDIM + l] = v;
            }
        }
    }
}

// ---------------------------------------------------------------------------
// Causal depthwise conv1d (K=4) + bias + SiLU. xin [b][l][d] -> u [b][l][d].
// ---------------------------------------------------------------------------
__global__ __launch_bounds__(256)
void dwconv_silu_kernel(const float* __restrict__ Xin, const float* __restrict__ W,
                        const float* __restrict__ bias, float* __restrict__ U) {
    const int dch = blockIdx.x * 256 + threadIdx.x;      // 0..767
    const int l = blockIdx.y, b = blockIdx.z;
    const float4 w4 = ((const float4*)W)[dch];
    const float wk[4] = {w4.x, w4.y, w4.z, w4.w};
    const float* xp = Xin + ((size_t)b * 4096 + l) * DINC + dch;
    float acc = bias[dch];
#pragma unroll
    for (int k = 0; k < 4; ++k) {
        const int ll = l - 3 + k;
        if (ll >= 0) acc = fmaf(xp[(k - 3) * DINC], wk[k], acc);
    }
    U[((size_t)b * 4096 + l) * DINC + dch] = acc / (1.f + __expf(-acc));
}

// ---------------------------------------------------------------------------
// Selective scan. grid (DIN/256=3, B=4). Thread owns (b,d): h[16] in regs.
// B_t/C_t staged per 64-token chunk in LDS (broadcast reads). dt/u/z
// prefetched one step ahead (independent of the h-chain) to hide L2 latency.
// Fuses: +u*D_skip, *silu(z). Writes y in place over DT (read-then-write).
// ---------------------------------------------------------------------------
__global__ __launch_bounds__(256)
void scan_kernel(float* __restrict__ DT, const float* __restrict__ U,
                 const float* __restrict__ DBL, const float* __restrict__ Z,
                 const float* __restrict__ A_log, const float* __restrict__ D_skip) {
    const int b = blockIdx.y;
    const int dch = blockIdx.x * 256 + threadIdx.x;
    float Arow[16];
#pragma unroll
    for (int n = 0; n < NST; ++n) Arow[n] = -__expf(A_log[dch * NST + n]);
    const float Dsk = D_skip[dch];
    float h[16];
#pragma unroll
    for (int n = 0; n < NST; ++n) h[n] = 0.f;

    __shared__ float bc[64][32];                         // [li][B(16)|C(16)]
    const size_t tokbase = (size_t)b * 4096;
    size_t off = tokbase * DINC + dch;
    float cdt = DT[off], cu = U[off], cz = Z[off];

    for (int l = 0; l < 4096; ++l) {
        const int li = l & 63;
        if (li == 0) {
            __syncthreads();
#pragma unroll
            for (int idx = 0; idx < 8; ++idx) {
                const int e = idx * 256 + threadIdx.x;
                bc[e >> 5][e & 31] = DBL[(tokbase + l + (e >> 5)) * 56 + 24 + (e & 31)];
            }
            __syncthreads();
        }
        float ndt = 0.f, nu = 0.f, nz = 0.f;
        if (l < 4095) {                                  // prefetch next step
            ndt = DT[off + DINC]; nu = U[off + DINC]; nz = Z[off + DINC];
        }
        const float du = cdt * cu;
        float y = 0.f;
#pragma unroll
        for (int n = 0; n < NST; ++n) {
            const float dA = __expf(cdt * Arow[n]);
            h[n] = dA * h[n] + du * bc[li][n];
            y = fmaf(h[n], bc[li][16 + n], y);
        }
        y += cu * Dsk;
        const float sz = cz / (1.f + __expf(-cz));
        DT[off] = y * sz;
        off += DINC;
        cdt = ndt; cu = nu; cz = nz;
    }
}

// ---------------------------------------------------------------------------
extern "C" void kernel_launch(void* const* d_in, const int* in_sizes, int n_in,
                              void* d_out, int out_size, void* d_ws, size_t ws_size,
                              hipStream_t stream) {
    (void)in_sizes; (void)n_in; (void)out_size; (void)ws_size;
    const float* x         = (const float*)d_in[0];
    const float* w1        = (const float*)d_in[1];
    const float* w2        = (const float*)d_in[3];
    const float* w3        = (const float*)d_in[5];
    const float* w4        = (const float*)d_in[7];
    const float* ln_g      = (const float*)d_in[9];
    const float* ln_b      = (const float*)d_in[10];
    const float* in_proj_w = (const float*)d_in[11];
    const float* conv1d_w  = (const float*)d_in[12];
    const float* conv1d_b  = (const float*)d_in[13];
    const float* x_proj_w  = (const float*)d_in[14];
    const float* dt_proj_w = (const float*)d_in[15];
    const float* dt_proj_b = (const float*)d_in[16];
    const float* A_log     = (const float*)d_in[17];
    const float* D_skip    = (const float*)d_in[18];
    const float* out_proj_w= (const float*)d_in[19];
    float* out = (float*)d_out;

    // Workspace layout (floats). Lifetimes are disjoint where regions alias.
    float* ws  = (float*)d_ws;
    float* A   = ws;                   //  6291456  [B,C,S] (also DBL later)
    float* Bb  = ws + 6291456;         //  6291456  [B,C,S]
    float* X1  = ws + 12582912;        // 12582912  xin (WT early, DT late)
    float* X2  = ws + 25165824;        // 12582912  z   (STATS early)
    float* U   = ws + 37748736;        // 12582912  u
    float* WT    = X1;                 // 3981312 <= 12582912
    float* STATS = X2;                 // 3072 floats, conv phase only
    float* DBL   = A;                  // 16384*56, after A (tn) is consumed
    float* DTb   = X1;                 // dt/y, after X1 (xin) is consumed
    const long CS = (long)CDIM * SDIM; // 1572864

    const dim3 convGrid(16, 48, 4);
    const int ewGrid = (BDIM * CDIM * SDIM / 4) / 256;   // 6144

    // ---- GSC: conv1 -> IN -> relu
    transpose_w_kernel<<<15552, 256, 0, stream>>>(w1, WT);
    conv3x3_kernel<<<convGrid, 256, 0, stream>>>(x, WT, A);
    inorm_stats_kernel<<<1536, 256, 0, stream>>>(A, STATS);
    norm_relu_kernel<<<ewGrid, 256, 0, stream>>>(A, STATS, nullptr, A);
    // ---- conv2 -> IN -> relu
    transpose_w_kernel<<<15552, 256, 0, stream>>>(w2, WT);
    conv3x3_kernel<<<convGrid, 256, 0, stream>>>(A, WT, Bb);
    inorm_stats_kernel<<<1536, 256, 0, stream>>>(Bb, STATS);
    norm_relu_kernel<<<ewGrid, 256, 0, stream>>>(Bb, STATS, nullptr, Bb);
    // ---- conv3 (1x1, per-batch GEMM) -> IN -> relu, + x1 path => A = x1+x2
    gemm_kernel<false, 0><<<dim3(64, 3, 4), 256, 0, stream>>>(
        w3, x, A, nullptr, nullptr, CDIM, SDIM, CDIM, CDIM, SDIM, SDIM, 0, CS, CS);
    inorm_stats_kernel<<<1536, 256, 0, stream>>>(A, STATS);
    norm_relu_kernel<<<ewGrid, 256, 0, stream>>>(A, STATS, Bb, A);
    // ---- conv4 (1x1) -> IN -> relu, + x residual => Bb = xg
    gemm_kernel<false, 0><<<dim3(64, 3, 4), 256, 0, stream>>>(
        w4, A, Bb, nullptr, nullptr, CDIM, SDIM, CDIM, CDIM, SDIM, SDIM, 0, CS, CS);
    inorm_stats_kernel<<<1536, 256, 0, stream>>>(Bb, STATS);
    norm_relu_kernel<<<ewGrid, 256, 0, stream>>>(Bb, STATS, x, Bb);
    // ---- LayerNorm + transpose: Bb [b][c][s] -> A = tn [b][l][c]
    layernorm_kernel<<<4096, 256, 0, stream>>>(Bb, ln_g, ln_b, A);
    // ---- in_proj: [16384,384] x [1536,384]^T -> split X1 (xin), X2 (z)
    gemm_kernel<true, 1><<<dim3(24, 128, 1), 256, 0, stream>>>(
        A, in_proj_w, X1, X2, nullptr, 16384, 1536, CDIM, CDIM, CDIM, DINC, 0, 0, 0);
    // ---- causal depthwise conv + SiLU -> U
    dwconv_silu_kernel<<<dim3(3, 4096, 4), 256, 0, stream>>>(X1, conv1d_w, conv1d_b, U);
    // ---- x_proj: [16384,768] x [56,768]^T -> DBL [16384,56]
    gemm_kernel<true, 0><<<dim3(1, 128, 1), 256, 0, stream>>>(
        U, x_proj_w, DBL, nullptr, nullptr, 16384, 56, DINC, DINC, DINC, 56, 0, 0, 0);
    // ---- dt_proj: [16384,24] x [768,24]^T + bias, softplus -> DTb [16384,768]
    gemm_kernel<true, 2><<<dim3(12, 128, 1), 256, 0, stream>>>(
        DBL, dt_proj_w, DTb, nullptr, dt_proj_b, 16384, DINC, 24, 56, 24, DINC, 0, 0, 0);
    // ---- selective scan (fuses +u*D, *silu(z)); writes y over DTb
    scan_kernel<<<dim3(3, 4), 256, 0, stream>>>(DTb, U, DBL, X2, A_log, D_skip);
    // ---- out_proj: [16384,768] x [384,768]^T -> d_out (transposed store)
    gemm_kernel<true, 3><<<dim3(6, 128, 1), 256, 0, stream>>>(
        DTb, out_proj_w, out, nullptr, nullptr, 16384, CDIM, DINC, DINC, DINC, 0, 0, 0, 0);
}

// Round 2
// 3358.345 us; speedup vs baseline: 2.2305x; 2.2305x over previous
//
#include <hip/hip_runtime.h>
#include <math.h>

#define CDIM 384
#define SDIM 4096
#define BDIM 4
#define DINC 768
#define NST  16

typedef unsigned short ushort_t;
typedef unsigned int uint_t;
typedef __attribute__((ext_vector_type(4))) float f32x4;
typedef __attribute__((ext_vector_type(8))) short bf16x8;

__device__ __forceinline__ ushort_t f2bf(float f) {
    union { float f; uint_t u; } v; v.f = f;
    uint_t r = v.u + 0x7FFFu + ((v.u >> 16) & 1u);   // round-to-nearest-even
    return (ushort_t)(r >> 16);
}

// ---------------------------------------------------------------------------
// Weight convert: W[co][ci][27] fp32 -> Wb[tap][co][ci] bf16.
// Reads contiguous (27 per thread), writes wave-coalesced along ci.
// ---------------------------------------------------------------------------
__global__ __launch_bounds__(256)
void wconv_kernel(const float* __restrict__ W, ushort_t* __restrict__ Wb) {
    const int idx = blockIdx.x * 256 + threadIdx.x;      // co*384 + ci
    const float* wp = W + (size_t)idx * 27;
#pragma unroll
    for (int tap = 0; tap < 27; ++tap)
        Wb[(size_t)tap * (CDIM * CDIM) + idx] = f2bf(wp[tap]);
}

// ---------------------------------------------------------------------------
// Pad + transpose to channels-last bf16: src[b][c][16^3] -> Xp[b][18][18][18][384]
// (interior only; borders pre-zeroed by memset). Reads L1-resident strided,
// writes 768B-coalesced per w.
// ---------------------------------------------------------------------------
__global__ __launch_bounds__(384)
void pad_kernel(const float* __restrict__ src, ushort_t* __restrict__ Xp) {
    const int blk = blockIdx.x;                          // b(4) d(16) h(16)
    const int b = blk >> 8, d = (blk >> 4) & 15, h = blk & 15;
    const int ci = threadIdx.x;
    const float* sp = src + (size_t)(b * CDIM + ci) * SDIM + d * 256 + h * 16;
    ushort_t* dp = Xp + ((((size_t)(b * 18 + d + 1) * 18) + (h + 1)) * 18 + 1) * CDIM + ci;
#pragma unroll
    for (int w = 0; w < 16; ++w)
        dp[(size_t)w * CDIM] = f2bf(sp[w]);
}

// ---------------------------------------------------------------------------
// Implicit-GEMM 3x3x3 conv via MFMA bf16 (fp32 accum).
// grid = (128 n-tiles [b,d,h-half], 3 co-tiles). Block 128co x 128s, 4 waves
// (2x2), wave tile 64x64 -> 16 mfma_f32_16x16x32_bf16 per K=32 chunk.
// K loop: 27 taps x 12 ci-chunks, LDS double-buffered, async-split staging.
// LDS rows padded to 40 bf16 (80B): b128 start banks tile all 8 slots.
// Conv bias omitted (zeros in this model; cancels through InstanceNorm anyway).
// ---------------------------------------------------------------------------
__global__ __launch_bounds__(256)
void conv_mfma_kernel(const ushort_t* __restrict__ Xp, const ushort_t* __restrict__ Wb,
                      float* __restrict__ Y) {
    const int nt = blockIdx.x;
    const int b  = nt >> 5;
    const int d  = (nt >> 1) & 15;
    const int h0 = (nt & 1) * 8;
    const int co0 = blockIdx.y * 128;
    const int t = threadIdx.x;
    const int lane = t & 63;
    const int wid = t >> 6;
    const int wy = wid >> 1, wx = wid & 1;

    __shared__ ushort_t As[2][128 * 40];
    __shared__ ushort_t Bs[2][128 * 40];

    f32x4 acc[4][4];
#pragma unroll
    for (int i = 0; i < 4; ++i)
#pragma unroll
        for (int j = 0; j < 4; ++j) acc[i][j] = (f32x4){0.f, 0.f, 0.f, 0.f};

    // staging role: thread -> (row = t>>1, ci-half = t&1) for both A (row=co)
    // and B (row=n). 16 bf16 = 2x uint4 loads + 2x b128 LDS writes.
    const int arow = t >> 1, half = t & 1;
    const int hl = arow >> 4, w = arow & 15;             // B voxel within tile
    const size_t wbase = (size_t)(co0 + arow) * CDIM + half * 16;
    const int wA = arow * 40 + half * 16;

    const int lm = lane & 15, lk = (lane >> 4) * 8;
    const int rA0 = (wy * 64 + lm) * 40 + lk;
    const int rB0 = (wx * 64 + lm) * 40 + lk;

    uint4 ra0, ra1, rb0, rb1;

    auto loadg = [&](int idx) {
        const int tap = idx / 12, chunk = idx - tap * 12;
        const int kd = tap / 9, r9 = tap - kd * 9;
        const int kh = r9 / 3, kw = r9 - kh * 3;
        const uint4* pa = reinterpret_cast<const uint4*>(
            Wb + (size_t)tap * (CDIM * CDIM) + wbase + chunk * 32);
        ra0 = pa[0]; ra1 = pa[1];
        const size_t voff = ((((size_t)(b * 18 + d + kd) * 18) + (h0 + hl + kh)) * 18
                             + (w + kw)) * CDIM + chunk * 32 + half * 16;
        const uint4* pb = reinterpret_cast<const uint4*>(Xp + voff);
        rb0 = pb[0]; rb1 = pb[1];
    };
    auto lwrite = [&](int buf) {
        *reinterpret_cast<uint4*>(&As[buf][wA])     = ra0;
        *reinterpret_cast<uint4*>(&As[buf][wA + 8]) = ra1;
        *reinterpret_cast<uint4*>(&Bs[buf][wA])     = rb0;
        *reinterpret_cast<uint4*>(&Bs[buf][wA + 8]) = rb1;
    };

    loadg(0);
    lwrite(0);
    __syncthreads();

    int buf = 0;
    for (int idx = 0; idx < 27 * 12; ++idx) {
        const bool more = (idx + 1) < 27 * 12;
        if (more) loadg(idx + 1);                        // issue early (T14)
        bf16x8 af[4], bfr[4];
#pragma unroll
        for (int mi = 0; mi < 4; ++mi)
            af[mi] = *reinterpret_cast<const bf16x8*>(&As[buf][rA0 + mi * 16 * 40]);
#pragma unroll
        for (int ni = 0; ni < 4; ++ni)
            bfr[ni] = *reinterpret_cast<const bf16x8*>(&Bs[buf][rB0 + ni * 16 * 40]);
#pragma unroll
        for (int mi = 0; mi < 4; ++mi)
#pragma unroll
            for (int ni = 0; ni < 4; ++ni)
                acc[mi][ni] = __builtin_amdgcn_mfma_f32_16x16x32_bf16(
                    af[mi], bfr[ni], acc[mi][ni], 0, 0, 0);
        if (more) lwrite(buf ^ 1);                       // write late
        __syncthreads();
        buf ^= 1;
    }

    // epilogue: C/D layout col=lane&15 (n), row=(lane>>4)*4+reg (co)
    const int coB = co0 + wy * 64 + (lane >> 4) * 4;
    const int nB  = wx * 64 + lm;
#pragma unroll
    for (int mi = 0; mi < 4; ++mi) {
#pragma unroll
        for (int ni = 0; ni < 4; ++ni) {
            const int nl = nB + ni * 16;
            const int s = d * 256 + (h0 + (nl >> 4)) * 16 + (nl & 15);
            float* yp = Y + ((size_t)b * CDIM + (coB + mi * 16)) * SDIM + s;
#pragma unroll
            for (int j = 0; j < 4; ++j)
                yp[(size_t)j * SDIM] = acc[mi][ni][j];
        }
    }
}

// ---------------------------------------------------------------------------
// InstanceNorm stats: one block per (b,c); mean + rsqrt(var+eps) (biased var).
// ---------------------------------------------------------------------------
__global__ __launch_bounds__(256)
void inorm_stats_kernel(const float* __restrict__ X, float* __restrict__ stats) {
    const int bc = blockIdx.x;                           // B*C = 1536
    const float* xp = X + (size_t)bc * SDIM;
    float s = 0.f, ss = 0.f;
    for (int i = threadIdx.x * 4; i < SDIM; i += 1024) {
        float4 v = *(const float4*)(xp + i);
        s += v.x + v.y + v.z + v.w;
        ss += v.x * v.x + v.y * v.y + v.z * v.z + v.w * v.w;
    }
#pragma unroll
    for (int off = 32; off > 0; off >>= 1) {
        s += __shfl_down(s, off);
        ss += __shfl_down(ss, off);
    }
    __shared__ float rs[4], rss[4];
    const int wid = threadIdx.x >> 6;
    if ((threadIdx.x & 63) == 0) { rs[wid] = s; rss[wid] = ss; }
    __syncthreads();
    if (threadIdx.x == 0) {
        float S = rs[0] + rs[1] + rs[2] + rs[3];
        float SS = rss[0] + rss[1] + rss[2] + rss[3];
        float m = S * (1.f / SDIM);
        float var = SS * (1.f / SDIM) - m * m;
        stats[bc * 2] = m;
        stats[bc * 2 + 1] = rsqrtf(var + 1e-5f);
    }
}

// ---------------------------------------------------------------------------
// y = relu((x-m)*rstd) [+ res]  — elementwise float4; Out may alias X.
// ---------------------------------------------------------------------------
__global__ __launch_bounds__(256)
void norm_relu_kernel(const float* __restrict__ X, const float* __restrict__ stats,
                      const float* __restrict__ Res, float* __restrict__ Out) {
    const size_t idx = (size_t)blockIdx.x * 256 + threadIdx.x;
    const size_t i4 = idx * 4;
    const int bc = (int)(i4 >> 12);
    const float m = stats[bc * 2], r = stats[bc * 2 + 1];
    float4 v = *(const float4*)(X + i4);
    float4 o;
    o.x = fmaxf((v.x - m) * r, 0.f);
    o.y = fmaxf((v.y - m) * r, 0.f);
    o.z = fmaxf((v.z - m) * r, 0.f);
    o.w = fmaxf((v.w - m) * r, 0.f);
    if (Res) {
        float4 q = *(const float4*)(Res + i4);
        o.x += q.x; o.y += q.y; o.z += q.z; o.w += q.w;
    }
    *(float4*)(Out + i4) = o;
}

// ---------------------------------------------------------------------------
// LayerNorm over C with transpose: xg [b][c][s] -> tn [b][l][c].
// ---------------------------------------------------------------------------
__global__ __launch_bounds__(256)
void layernorm_kernel(const float* __restrict__ Xg, const float* __restrict__ gam,
                      const float* __restrict__ bet, float* __restrict__ Tn) {
    const int token = blockIdx.x * 4 + (threadIdx.x >> 6);
    const int lane = threadIdx.x & 63;
    const int b = token >> 12, l = token & 4095;
    const float* xp = Xg + (size_t)b * CDIM * SDIM + l;
    float v[6];
    float s = 0.f, ss = 0.f;
#pragma unroll
    for (int i = 0; i < 6; ++i) {
        v[i] = xp[(size_t)(lane + i * 64) * SDIM];
        s += v[i]; ss += v[i] * v[i];
    }
#pragma unroll
    for (int off = 32; off > 0; off >>= 1) {
        s += __shfl_down(s, off);
        ss += __shfl_down(ss, off);
    }
    s = __shfl(s, 0); ss = __shfl(ss, 0);
    const float m = s * (1.f / CDIM);
    const float r = rsqrtf(ss * (1.f / CDIM) - m * m + 1e-5f);
    float* tp = Tn + (size_t)token * CDIM;
#pragma unroll
    for (int i = 0; i < 6; ++i) {
        const int c = lane + i * 64;
        tp[c] = (v[i] - m) * r * gam[c] + bet[c];
    }
}

// ---------------------------------------------------------------------------
// Tiled fp32 GEMM (unchanged from round 1). C[M,N] = A[M,K] x B.
// ---------------------------------------------------------------------------
template<bool NT, int EPI>
__global__ __launch_bounds__(256)
void gemm_kernel(const float* __restrict__ A, const float* __restrict__ B,
                 float* __restrict__ C, float* __restrict__ C2,
                 const float* __restrict__ bias,
                 int M, int N, int K, int lda, int ldb, int ldc,
                 long sA, long sB, long sC) {
    __shared__ __align__(16) float As[16][132];
    __shared__ __align__(16) float Bs[16][68];
    const int t = threadIdx.x;
    const int m0 = blockIdx.y * 128;
    const int n0 = blockIdx.x * 64;
    A += (long)blockIdx.z * sA;
    B += (long)blockIdx.z * sB;
    C += (long)blockIdx.z * sC;

    float acc[8][4];
#pragma unroll
    for (int i = 0; i < 8; ++i)
#pragma unroll
        for (int j = 0; j < 4; ++j) acc[i][j] = 0.f;

    const int mr = (t & 15) * 8;
    const int nr = (t >> 4) * 4;

    for (int k0 = 0; k0 < K; k0 += 16) {
#pragma unroll
        for (int idx = 0; idx < 8; ++idx) {
            const int e = idx * 256 + t;
            const int k = e & 15, m = e >> 4;
            float v = 0.f;
            if (k0 + k < K) v = A[(size_t)(m0 + m) * lda + (k0 + k)];
            As[k][m] = v;
        }
#pragma unroll
        for (int idx = 0; idx < 4; ++idx) {
            const int e = idx * 256 + t;
            if (NT) {
                const int k = e & 15, n = e >> 4;
                float v = 0.f;
                if ((n0 + n) < N && (k0 + k) < K) v = B[(size_t)(n0 + n) * ldb + (k0 + k)];
                Bs[k][n] = v;
            } else {
                const int n = e & 63, k = e >> 6;
                float v = 0.f;
                if ((n0 + n) < N && (k0 + k) < K) v = B[(size_t)(k0 + k) * ldb + (n0 + n)];
                Bs[k][n] = v;
            }
        }
        __syncthreads();
#pragma unroll
        for (int k = 0; k < 16; ++k) {
            float4 a0 = *(const float4*)&As[k][mr];
            float4 a1 = *(const float4*)&As[k][mr + 4];
            float4 b0 = *(const float4*)&Bs[k][nr];
            const float av[8] = {a0.x, a0.y, a0.z, a0.w, a1.x, a1.y, a1.z, a1.w};
            const float bv[4] = {b0.x, b0.y, b0.z, b0.w};
#pragma unroll
            for (int i = 0; i < 8; ++i)
#pragma unroll
                for (int j = 0; j < 4; ++j)
                    acc[i][j] = fmaf(av[i], bv[j], acc[i][j]);
        }
        __syncthreads();
    }

#pragma unroll
    for (int i = 0; i < 8; ++i) {
        const int m = m0 + mr + i;
#pragma unroll
        for (int j = 0; j < 4; ++j) {
            const int n = n0 + nr + j;
            if (n >= N) continue;
            float v = acc[i][j];
            if (EPI == 0) {
                C[(size_t)m * ldc + n] = v;
            } else if (EPI == 1) {
                if (n < DINC) C[(size_t)m * DINC + n] = v;
                else          C2[(size_t)m * DINC + (n - DINC)] = v;
            } else if (EPI == 2) {
                v += bias[n];
                v = (v > 20.f) ? v : log1pf(__expf(v));
                C[(size_t)m * ldc + n] = v;
            } else {
                const int bb = m >> 12, l = m & 4095;
                C[((size_t)bb * CDIM + n) * SDIM + l] = v;
            }
        }
    }
}

// ---------------------------------------------------------------------------
// Causal depthwise conv1d (K=4) + bias + SiLU.
// ---------------------------------------------------------------------------
__global__ __launch_bounds__(256)
void dwconv_silu_kernel(const float* __restrict__ Xin, const float* __restrict__ W,
                        const float* __restrict__ bias, float* __restrict__ U) {
    const int dch = blockIdx.x * 256 + threadIdx.x;
    const int l = blockIdx.y, b = blockIdx.z;
    const float4 w4 = ((const float4*)W)[dch];
    const float wk[4] = {w4.x, w4.y, w4.z, w4.w};
    const float* xp = Xin + ((size_t)b * 4096 + l) * DINC + dch;
    float acc = bias[dch];
#pragma unroll
    for (int k = 0; k < 4; ++k) {
        const int ll = l - 3 + k;
        if (ll >= 0) acc = fmaf(xp[(k - 3) * DINC], wk[k], acc);
    }
    U[((size_t)b * 4096 + l) * DINC + dch] = acc / (1.f + __expf(-acc));
}

// ---------------------------------------------------------------------------
// Selective scan (fuses +u*D_skip, *silu(z)); writes y over DT.
// ---------------------------------------------------------------------------
__global__ __launch_bounds__(256)
void scan_kernel(float* __restrict__ DT, const float* __restrict__ U,
                 const float* __restrict__ DBL, const float* __restrict__ Z,
                 const float* __restrict__ A_log, const float* __restrict__ D_skip) {
    const int b = blockIdx.y;
    const int dch = blockIdx.x * 256 + threadIdx.x;
    float Arow[16];
#pragma unroll
    for (int n = 0; n < NST; ++n) Arow[n] = -__expf(A_log[dch * NST + n]);
    const float Dsk = D_skip[dch];
    float h[16];
#pragma unroll
    for (int n = 0; n < NST; ++n) h[n] = 0.f;

    __shared__ float bc[64][32];
    const size_t tokbase = (size_t)b * 4096;
    size_t off = tokbase * DINC + dch;
    float cdt = DT[off], cu = U[off], cz = Z[off];

    for (int l = 0; l < 4096; ++l) {
        const int li = l & 63;
        if (li == 0) {
            __syncthreads();
#pragma unroll
            for (int idx = 0; idx < 8; ++idx) {
                const int e = idx * 256 + threadIdx.x;
                bc[e >> 5][e & 31] = DBL[(tokbase + l + (e >> 5)) * 56 + 24 + (e & 31)];
            }
            __syncthreads();
        }
        float ndt = 0.f, nu = 0.f, nz = 0.f;
        if (l < 4095) {
            ndt = DT[off + DINC]; nu = U[off + DINC]; nz = Z[off + DINC];
        }
        const float du = cdt * cu;
        float y = 0.f;
#pragma unroll
        for (int n = 0; n < NST; ++n) {
            const float dA = __expf(cdt * Arow[n]);
            h[n] = dA * h[n] + du * bc[li][n];
            y = fmaf(h[n], bc[li][16 + n], y);
        }
        y += cu * Dsk;
        const float sz = cz / (1.f + __expf(-cz));
        DT[off] = y * sz;
        off += DINC;
        cdt = ndt; cu = nu; cz = nz;
    }
}

// ---------------------------------------------------------------------------
extern "C" void kernel_launch(void* const* d_in, const int* in_sizes, int n_in,
                              void* d_out, int out_size, void* d_ws, size_t ws_size,
                              hipStream_t stream) {
    (void)in_sizes; (void)n_in; (void)out_size; (void)ws_size;
    const float* x         = (const float*)d_in[0];
    const float* w1        = (const float*)d_in[1];
    const float* w2        = (const float*)d_in[3];
    const float* w3        = (const float*)d_in[5];
    const float* w4        = (const float*)d_in[7];
    const float* ln_g      = (const float*)d_in[9];
    const float* ln_b      = (const float*)d_in[10];
    const float* in_proj_w = (const float*)d_in[11];
    const float* conv1d_w  = (const float*)d_in[12];
    const float* conv1d_b  = (const float*)d_in[13];
    const float* x_proj_w  = (const float*)d_in[14];
    const float* dt_proj_w = (const float*)d_in[15];
    const float* dt_proj_b = (const float*)d_in[16];
    const float* A_log     = (const float*)d_in[17];
    const float* D_skip    = (const float*)d_in[18];
    const float* out_proj_w= (const float*)d_in[19];
    float* out = (float*)d_out;

    // Workspace layout (floats). Lifetimes disjoint where regions alias.
    float* ws  = (float*)d_ws;
    float* A   = ws;                   //  6291456  [B,C,S]
    float* Bb  = ws + 6291456;         //  6291456  [B,C,S]
    float* X1  = ws + 12582912;        // 12582912  xin (conv phase: Wb+Xpad)
    float* X2  = ws + 25165824;        // 12582912  z   (STATS early)
    float* U   = ws + 37748736;        // 12582912  u
    float* STATS = X2;
    float* DBL   = A;                  // 16384*56, after A (tn) consumed
    float* DTb   = X1;                 // dt/y, after X1 (xin) consumed
    ushort_t* Wb = (ushort_t*)(X1);                  // 3,981,312 bf16 = 7.96MB
    ushort_t* Xp = (ushort_t*)(X1 + 2097152);        // 8,957,952 bf16 = 17.9MB
    const size_t XP_BYTES = (size_t)4 * 18 * 18 * 18 * CDIM * 2;
    const long CS = (long)CDIM * SDIM;

    const int ewGrid = (BDIM * CDIM * SDIM / 4) / 256;   // 6144

    // ---- GSC: conv1 (MFMA) -> IN -> relu
    hipMemsetAsync(Xp, 0, XP_BYTES, stream);             // zero pad borders
    wconv_kernel<<<576, 256, 0, stream>>>(w1, Wb);
    pad_kernel<<<1024, 384, 0, stream>>>(x, Xp);
    conv_mfma_kernel<<<dim3(128, 3), 256, 0, stream>>>(Xp, Wb, A);
    inorm_stats_kernel<<<1536, 256, 0, stream>>>(A, STATS);
    norm_relu_kernel<<<ewGrid, 256, 0, stream>>>(A, STATS, nullptr, A);
    // ---- conv2 (MFMA) -> IN -> relu
    wconv_kernel<<<576, 256, 0, stream>>>(w2, Wb);
    pad_kernel<<<1024, 384, 0, stream>>>(A, Xp);         // borders still zero
    conv_mfma_kernel<<<dim3(128, 3), 256, 0, stream>>>(Xp, Wb, Bb);
    inorm_stats_kernel<<<1536, 256, 0, stream>>>(Bb, STATS);
    norm_relu_kernel<<<ewGrid, 256, 0, stream>>>(Bb, STATS, nullptr, Bb);
    // ---- conv3 (1x1) -> IN -> relu, + x1 path => A = x1+x2
    gemm_kernel<false, 0><<<dim3(64, 3, 4), 256, 0, stream>>>(
        w3, x, A, nullptr, nullptr, CDIM, SDIM, CDIM, CDIM, SDIM, SDIM, 0, CS, CS);
    inorm_stats_kernel<<<1536, 256, 0, stream>>>(A, STATS);
    norm_relu_kernel<<<ewGrid, 256, 0, stream>>>(A, STATS, Bb, A);
    // ---- conv4 (1x1) -> IN -> relu, + x residual => Bb = xg
    gemm_kernel<false, 0><<<dim3(64, 3, 4), 256, 0, stream>>>(
        w4, A, Bb, nullptr, nullptr, CDIM, SDIM, CDIM, CDIM, SDIM, SDIM, 0, CS, CS);
    inorm_stats_kernel<<<1536, 256, 0, stream>>>(Bb, STATS);
    norm_relu_kernel<<<ewGrid, 256, 0, stream>>>(Bb, STATS, x, Bb);
    // ---- LayerNorm + transpose: Bb [b][c][s] -> A = tn [b][l][c]
    layernorm_kernel<<<4096, 256, 0, stream>>>(Bb, ln_g, ln_b, A);
    // ---- in_proj: [16384,384] x [1536,384]^T -> split X1 (xin), X2 (z)
    gemm_kernel<true, 1><<<dim3(24, 128, 1), 256, 0, stream>>>(
        A, in_proj_w, X1, X2, nullptr, 16384, 1536, CDIM, CDIM, CDIM, DINC, 0, 0, 0);
    // ---- causal depthwise conv + SiLU -> U
    dwconv_silu_kernel<<<dim3(3, 4096, 4), 256, 0, stream>>>(X1, conv1d_w, conv1d_b, U);
    // ---- x_proj: [16384,768] x [56,768]^T -> DBL [16384,56]
    gemm_kernel<true, 0><<<dim3(1, 128, 1), 256, 0, stream>>>(
        U, x_proj_w, DBL, nullptr, nullptr, 16384, 56, DINC, DINC, DINC, 56, 0, 0, 0);
    // ---- dt_proj: [16384,24] x [768,24]^T + bias, softplus -> DTb
    gemm_kernel<true, 2><<<dim3(12, 128, 1), 256, 0, stream>>>(
        DBL, dt_proj_w, DTb, nullptr, dt_proj_b, 16384, DINC, 24, 56, 24, DINC, 0, 0, 0);
    // ---- selective scan
    scan_kernel<<<dim3(3, 4), 256, 0, stream>>>(DTb, U, DBL, X2, A_log, D_skip);
    // ---- out_proj: [16384,768] x [384,768]^T -> d_out (transposed store)
    gemm_kernel<true, 3><<<dim3(6, 128, 1), 256, 0, stream>>>(
        DTb, out_proj_w, out, nullptr, nullptr, 16384, CDIM, DINC, DINC, DINC, 0, 0, 0, 0);
}

// Round 3
// 1646.667 us; speedup vs baseline: 4.5490x; 2.0395x over previous
//
#include <hip/hip_runtime.h>
#include <math.h>

#define CDIM 384
#define SDIM 4096
#define BDIM 4
#define DINC 768
#define NST  16
#define NCHUNK 64
#define LCHUNK 64

typedef unsigned short ushort_t;
typedef unsigned int uint_t;
typedef __attribute__((ext_vector_type(4))) float f32x4;
typedef __attribute__((ext_vector_type(8))) short bf16x8;

__device__ __forceinline__ ushort_t f2bf(float f) {
    union { float f; uint_t u; } v; v.f = f;
    uint_t r = v.u + 0x7FFFu + ((v.u >> 16) & 1u);   // round-to-nearest-even
    return (ushort_t)(r >> 16);
}

// ---------------------------------------------------------------------------
// Weight convert: W[co][ci][27] fp32 -> Wb[tap][co][ci] bf16.
// ---------------------------------------------------------------------------
__global__ __launch_bounds__(256)
void wconv_kernel(const float* __restrict__ W, ushort_t* __restrict__ Wb) {
    const int idx = blockIdx.x * 256 + threadIdx.x;      // co*384 + ci
    const float* wp = W + (size_t)idx * 27;
#pragma unroll
    for (int tap = 0; tap < 27; ++tap)
        Wb[(size_t)tap * (CDIM * CDIM) + idx] = f2bf(wp[tap]);
}

// ---------------------------------------------------------------------------
// Pad + transpose to channels-last bf16: src[b][c][16^3] -> Xp[b][18][18][18][384]
// ---------------------------------------------------------------------------
__global__ __launch_bounds__(384)
void pad_kernel(const float* __restrict__ src, ushort_t* __restrict__ Xp) {
    const int blk = blockIdx.x;                          // b(4) d(16) h(16)
    const int b = blk >> 8, d = (blk >> 4) & 15, h = blk & 15;
    const int ci = threadIdx.x;
    const float* sp = src + (size_t)(b * CDIM + ci) * SDIM + d * 256 + h * 16;
    ushort_t* dp = Xp + ((((size_t)(b * 18 + d + 1) * 18) + (h + 1)) * 18 + 1) * CDIM + ci;
#pragma unroll
    for (int w = 0; w < 16; ++w)
        dp[(size_t)w * CDIM] = f2bf(sp[w]);
}

// ---------------------------------------------------------------------------
// Implicit-GEMM 3x3x3 conv via MFMA bf16 (fp32 accum). (unchanged, round 2)
// ---------------------------------------------------------------------------
__global__ __launch_bounds__(256)
void conv_mfma_kernel(const ushort_t* __restrict__ Xp, const ushort_t* __restrict__ Wb,
                      float* __restrict__ Y) {
    const int nt = blockIdx.x;
    const int b  = nt >> 5;
    const int d  = (nt >> 1) & 15;
    const int h0 = (nt & 1) * 8;
    const int co0 = blockIdx.y * 128;
    const int t = threadIdx.x;
    const int lane = t & 63;
    const int wid = t >> 6;
    const int wy = wid >> 1, wx = wid & 1;

    __shared__ ushort_t As[2][128 * 40];
    __shared__ ushort_t Bs[2][128 * 40];

    f32x4 acc[4][4];
#pragma unroll
    for (int i = 0; i < 4; ++i)
#pragma unroll
        for (int j = 0; j < 4; ++j) acc[i][j] = (f32x4){0.f, 0.f, 0.f, 0.f};

    const int arow = t >> 1, half = t & 1;
    const int hl = arow >> 4, w = arow & 15;
    const size_t wbase = (size_t)(co0 + arow) * CDIM + half * 16;
    const int wA = arow * 40 + half * 16;

    const int lm = lane & 15, lk = (lane >> 4) * 8;
    const int rA0 = (wy * 64 + lm) * 40 + lk;
    const int rB0 = (wx * 64 + lm) * 40 + lk;

    uint4 ra0, ra1, rb0, rb1;

    auto loadg = [&](int idx) {
        const int tap = idx / 12, chunk = idx - tap * 12;
        const int kd = tap / 9, r9 = tap - kd * 9;
        const int kh = r9 / 3, kw = r9 - kh * 3;
        const uint4* pa = reinterpret_cast<const uint4*>(
            Wb + (size_t)tap * (CDIM * CDIM) + wbase + chunk * 32);
        ra0 = pa[0]; ra1 = pa[1];
        const size_t voff = ((((size_t)(b * 18 + d + kd) * 18) + (h0 + hl + kh)) * 18
                             + (w + kw)) * CDIM + chunk * 32 + half * 16;
        const uint4* pb = reinterpret_cast<const uint4*>(Xp + voff);
        rb0 = pb[0]; rb1 = pb[1];
    };
    auto lwrite = [&](int buf) {
        *reinterpret_cast<uint4*>(&As[buf][wA])     = ra0;
        *reinterpret_cast<uint4*>(&As[buf][wA + 8]) = ra1;
        *reinterpret_cast<uint4*>(&Bs[buf][wA])     = rb0;
        *reinterpret_cast<uint4*>(&Bs[buf][wA + 8]) = rb1;
    };

    loadg(0);
    lwrite(0);
    __syncthreads();

    int buf = 0;
    for (int idx = 0; idx < 27 * 12; ++idx) {
        const bool more = (idx + 1) < 27 * 12;
        if (more) loadg(idx + 1);
        bf16x8 af[4], bfr[4];
#pragma unroll
        for (int mi = 0; mi < 4; ++mi)
            af[mi] = *reinterpret_cast<const bf16x8*>(&As[buf][rA0 + mi * 16 * 40]);
#pragma unroll
        for (int ni = 0; ni < 4; ++ni)
            bfr[ni] = *reinterpret_cast<const bf16x8*>(&Bs[buf][rB0 + ni * 16 * 40]);
#pragma unroll
        for (int mi = 0; mi < 4; ++mi)
#pragma unroll
            for (int ni = 0; ni < 4; ++ni)
                acc[mi][ni] = __builtin_amdgcn_mfma_f32_16x16x32_bf16(
                    af[mi], bfr[ni], acc[mi][ni], 0, 0, 0);
        if (more) lwrite(buf ^ 1);
        __syncthreads();
        buf ^= 1;
    }

    const int coB = co0 + wy * 64 + (lane >> 4) * 4;
    const int nB  = wx * 64 + lm;
#pragma unroll
    for (int mi = 0; mi < 4; ++mi) {
#pragma unroll
        for (int ni = 0; ni < 4; ++ni) {
            const int nl = nB + ni * 16;
            const int s = d * 256 + (h0 + (nl >> 4)) * 16 + (nl & 15);
            float* yp = Y + ((size_t)b * CDIM + (coB + mi * 16)) * SDIM + s;
#pragma unroll
            for (int j = 0; j < 4; ++j)
                yp[(size_t)j * SDIM] = acc[mi][ni][j];
        }
    }
}

// ---------------------------------------------------------------------------
// InstanceNorm stats: one block per (b,c).
// ---------------------------------------------------------------------------
__global__ __launch_bounds__(256)
void inorm_stats_kernel(const float* __restrict__ X, float* __restrict__ stats) {
    const int bc = blockIdx.x;
    const float* xp = X + (size_t)bc * SDIM;
    float s = 0.f, ss = 0.f;
    for (int i = threadIdx.x * 4; i < SDIM; i += 1024) {
        float4 v = *(const float4*)(xp + i);
        s += v.x + v.y + v.z + v.w;
        ss += v.x * v.x + v.y * v.y + v.z * v.z + v.w * v.w;
    }
#pragma unroll
    for (int off = 32; off > 0; off >>= 1) {
        s += __shfl_down(s, off);
        ss += __shfl_down(ss, off);
    }
    __shared__ float rs[4], rss[4];
    const int wid = threadIdx.x >> 6;
    if ((threadIdx.x & 63) == 0) { rs[wid] = s; rss[wid] = ss; }
    __syncthreads();
    if (threadIdx.x == 0) {
        float S = rs[0] + rs[1] + rs[2] + rs[3];
        float SS = rss[0] + rss[1] + rss[2] + rss[3];
        float m = S * (1.f / SDIM);
        float var = SS * (1.f / SDIM) - m * m;
        stats[bc * 2] = m;
        stats[bc * 2 + 1] = rsqrtf(var + 1e-5f);
    }
}

// ---------------------------------------------------------------------------
// y = relu((x-m)*rstd) [+ res]
// ---------------------------------------------------------------------------
__global__ __launch_bounds__(256)
void norm_relu_kernel(const float* __restrict__ X, const float* __restrict__ stats,
                      const float* __restrict__ Res, float* __restrict__ Out) {
    const size_t idx = (size_t)blockIdx.x * 256 + threadIdx.x;
    const size_t i4 = idx * 4;
    const int bc = (int)(i4 >> 12);
    const float m = stats[bc * 2], r = stats[bc * 2 + 1];
    float4 v = *(const float4*)(X + i4);
    float4 o;
    o.x = fmaxf((v.x - m) * r, 0.f);
    o.y = fmaxf((v.y - m) * r, 0.f);
    o.z = fmaxf((v.z - m) * r, 0.f);
    o.w = fmaxf((v.w - m) * r, 0.f);
    if (Res) {
        float4 q = *(const float4*)(Res + i4);
        o.x += q.x; o.y += q.y; o.z += q.z; o.w += q.w;
    }
    *(float4*)(Out + i4) = o;
}

// ---------------------------------------------------------------------------
// LayerNorm over C with transpose: xg [b][c][s] -> tn [b][l][c].
// ---------------------------------------------------------------------------
__global__ __launch_bounds__(256)
void layernorm_kernel(const float* __restrict__ Xg, const float* __restrict__ gam,
                      const float* __restrict__ bet, float* __restrict__ Tn) {
    const int token = blockIdx.x * 4 + (threadIdx.x >> 6);
    const int lane = threadIdx.x & 63;
    const int b = token >> 12, l = token & 4095;
    const float* xp = Xg + (size_t)b * CDIM * SDIM + l;
    float v[6];
    float s = 0.f, ss = 0.f;
#pragma unroll
    for (int i = 0; i < 6; ++i) {
        v[i] = xp[(size_t)(lane + i * 64) * SDIM];
        s += v[i]; ss += v[i] * v[i];
    }
#pragma unroll
    for (int off = 32; off > 0; off >>= 1) {
        s += __shfl_down(s, off);
        ss += __shfl_down(ss, off);
    }
    s = __shfl(s, 0); ss = __shfl(ss, 0);
    const float m = s * (1.f / CDIM);
    const float r = rsqrtf(ss * (1.f / CDIM) - m * m + 1e-5f);
    float* tp = Tn + (size_t)token * CDIM;
#pragma unroll
    for (int i = 0; i < 6; ++i) {
        const int c = lane + i * 64;
        tp[c] = (v[i] - m) * r * gam[c] + bet[c];
    }
}

// ---------------------------------------------------------------------------
// Tiled fp32 GEMM (unchanged). C[M,N] = A[M,K] x B.
// ---------------------------------------------------------------------------
template<bool NT, int EPI>
__global__ __launch_bounds__(256)
void gemm_kernel(const float* __restrict__ A, const float* __restrict__ B,
                 float* __restrict__ C, float* __restrict__ C2,
                 const float* __restrict__ bias,
                 int M, int N, int K, int lda, int ldb, int ldc,
                 long sA, long sB, long sC) {
    __shared__ __align__(16) float As[16][132];
    __shared__ __align__(16) float Bs[16][68];
    const int t = threadIdx.x;
    const int m0 = blockIdx.y * 128;
    const int n0 = blockIdx.x * 64;
    A += (long)blockIdx.z * sA;
    B += (long)blockIdx.z * sB;
    C += (long)blockIdx.z * sC;

    float acc[8][4];
#pragma unroll
    for (int i = 0; i < 8; ++i)
#pragma unroll
        for (int j = 0; j < 4; ++j) acc[i][j] = 0.f;

    const int mr = (t & 15) * 8;
    const int nr = (t >> 4) * 4;

    for (int k0 = 0; k0 < K; k0 += 16) {
#pragma unroll
        for (int idx = 0; idx < 8; ++idx) {
            const int e = idx * 256 + t;
            const int k = e & 15, m = e >> 4;
            float v = 0.f;
            if (k0 + k < K) v = A[(size_t)(m0 + m) * lda + (k0 + k)];
            As[k][m] = v;
        }
#pragma unroll
        for (int idx = 0; idx < 4; ++idx) {
            const int e = idx * 256 + t;
            if (NT) {
                const int k = e & 15, n = e >> 4;
                float v = 0.f;
                if ((n0 + n) < N && (k0 + k) < K) v = B[(size_t)(n0 + n) * ldb + (k0 + k)];
                Bs[k][n] = v;
            } else {
                const int n = e & 63, k = e >> 6;
                float v = 0.f;
                if ((n0 + n) < N && (k0 + k) < K) v = B[(size_t)(k0 + k) * ldb + (n0 + n)];
                Bs[k][n] = v;
            }
        }
        __syncthreads();
#pragma unroll
        for (int k = 0; k < 16; ++k) {
            float4 a0 = *(const float4*)&As[k][mr];
            float4 a1 = *(const float4*)&As[k][mr + 4];
            float4 b0 = *(const float4*)&Bs[k][nr];
            const float av[8] = {a0.x, a0.y, a0.z, a0.w, a1.x, a1.y, a1.z, a1.w};
            const float bv[4] = {b0.x, b0.y, b0.z, b0.w};
#pragma unroll
            for (int i = 0; i < 8; ++i)
#pragma unroll
                for (int j = 0; j < 4; ++j)
                    acc[i][j] = fmaf(av[i], bv[j], acc[i][j]);
        }
        __syncthreads();
    }

#pragma unroll
    for (int i = 0; i < 8; ++i) {
        const int m = m0 + mr + i;
#pragma unroll
        for (int j = 0; j < 4; ++j) {
            const int n = n0 + nr + j;
            if (n >= N) continue;
            float v = acc[i][j];
            if (EPI == 0) {
                C[(size_t)m * ldc + n] = v;
            } else if (EPI == 1) {
                if (n < DINC) C[(size_t)m * DINC + n] = v;
                else          C2[(size_t)m * DINC + (n - DINC)] = v;
            } else if (EPI == 2) {
                v += bias[n];
                v = (v > 20.f) ? v : log1pf(__expf(v));
                C[(size_t)m * ldc + n] = v;
            } else {
                const int bb = m >> 12, l = m & 4095;
                C[((size_t)bb * CDIM + n) * SDIM + l] = v;
            }
        }
    }
}

// ---------------------------------------------------------------------------
// Causal depthwise conv1d (K=4) + bias + SiLU.
// ---------------------------------------------------------------------------
__global__ __launch_bounds__(256)
void dwconv_silu_kernel(const float* __restrict__ Xin, const float* __restrict__ W,
                        const float* __restrict__ bias, float* __restrict__ U) {
    const int dch = blockIdx.x * 256 + threadIdx.x;
    const int l = blockIdx.y, b = blockIdx.z;
    const float4 w4 = ((const float4*)W)[dch];
    const float wk[4] = {w4.x, w4.y, w4.z, w4.w};
    const float* xp = Xin + ((size_t)b * 4096 + l) * DINC + dch;
    float acc = bias[dch];
#pragma unroll
    for (int k = 0; k < 4; ++k) {
        const int ll = l - 3 + k;
        if (ll >= 0) acc = fmaf(xp[(k - 3) * DINC], wk[k], acc);
    }
    U[((size_t)b * 4096 + l) * DINC + dch] = acc / (1.f + __expf(-acc));
}

// ---------------------------------------------------------------------------
// Chunked parallel selective scan. The recurrence h_t = exp(dt_t*A)h_{t-1} +
// dt_t*u_t*B_t is linear; the chunk-to-chunk transition factor is
// exp(A * sum(dt over chunk)). Three phases:
//  p1: per (b,d,chunk): local scan from h=0 -> HOUT[b,d,chunk][16], SDT sum.
//  p2: per (b,d,n): 64-step exclusive scan over chunk summaries, in place.
//  p3: per (b,d,chunk): rerun seeded with HOUT (=h_in), emit y fused with
//      +u*D_skip and *silu(z), writing over DT.
// ---------------------------------------------------------------------------
__global__ __launch_bounds__(256)
void scan_phase1_kernel(const float* __restrict__ DT, const float* __restrict__ U,
                        const float* __restrict__ DBL, const float* __restrict__ A_log,
                        float* __restrict__ HOUT, float* __restrict__ SDT) {
    const int b = blockIdx.z, chunk = blockIdx.y;
    const int dch = blockIdx.x * 256 + threadIdx.x;
    float Arow[16];
#pragma unroll
    for (int n = 0; n < NST; ++n) Arow[n] = -__expf(A_log[dch * NST + n]);

    __shared__ float bcs[LCHUNK][16];
    const size_t tokbase = (size_t)b * 4096 + chunk * LCHUNK;
#pragma unroll
    for (int idx = 0; idx < 4; ++idx) {
        const int e = idx * 256 + threadIdx.x;
        bcs[e >> 4][e & 15] = DBL[(tokbase + (e >> 4)) * 56 + 24 + (e & 15)];
    }
    __syncthreads();

    size_t off = tokbase * DINC + dch;
    float h[16];
#pragma unroll
    for (int n = 0; n < NST; ++n) h[n] = 0.f;
    float sdt = 0.f;
    float cdt = DT[off], cu = U[off];
    for (int t = 0; t < LCHUNK; ++t) {
        float ndt = 0.f, nu = 0.f;
        if (t < LCHUNK - 1) { ndt = DT[off + DINC]; nu = U[off + DINC]; }
        sdt += cdt;
        const float du = cdt * cu;
#pragma unroll
        for (int n = 0; n < NST; ++n)
            h[n] = __expf(cdt * Arow[n]) * h[n] + du * bcs[t][n];
        off += DINC;
        cdt = ndt; cu = nu;
    }
    float* hp = HOUT + (((size_t)(b * DINC + dch) * NCHUNK + chunk) << 4);
#pragma unroll
    for (int n = 0; n < NST; ++n) hp[n] = h[n];
    SDT[(size_t)(b * DINC + dch) * NCHUNK + chunk] = sdt;
}

__global__ __launch_bounds__(256)
void scan_phase2_kernel(float* __restrict__ HOUT, const float* __restrict__ SDT,
                        const float* __restrict__ A_log) {
    const int t = blockIdx.x * 256 + threadIdx.x;        // 49152 = 4*768*16
    const int b = t / (DINC * NST);
    const int rem = t - b * (DINC * NST);
    const int d = rem >> 4, n = rem & 15;
    const float An = -__expf(A_log[d * NST + n]);
    float* hp = HOUT + (((size_t)(b * DINC + d) * NCHUNK) << 4) + n;
    const float* sp = SDT + (size_t)(b * DINC + d) * NCHUNK;
    float H = 0.f;
    for (int c = 0; c < NCHUNK; ++c) {
        const float tmp = hp[c * 16];
        const float dA = __expf(An * sp[c]);
        hp[c * 16] = H;                                  // exclusive prefix
        H = dA * H + tmp;
    }
}

__global__ __launch_bounds__(256)
void scan_phase3_kernel(float* __restrict__ DT, const float* __restrict__ U,
                        const float* __restrict__ DBL, const float* __restrict__ Z,
                        const float* __restrict__ A_log, const float* __restrict__ D_skip,
                        const float* __restrict__ HOUT) {
    const int b = blockIdx.z, chunk = blockIdx.y;
    const int dch = blockIdx.x * 256 + threadIdx.x;
    float Arow[16];
#pragma unroll
    for (int n = 0; n < NST; ++n) Arow[n] = -__expf(A_log[dch * NST + n]);
    const float Dsk = D_skip[dch];

    __shared__ float bcs[LCHUNK][32];                    // [t][B(16)|C(16)]
    const size_t tokbase = (size_t)b * 4096 + chunk * LCHUNK;
#pragma unroll
    for (int idx = 0; idx < 8; ++idx) {
        const int e = idx * 256 + threadIdx.x;
        bcs[e >> 5][e & 31] = DBL[(tokbase + (e >> 5)) * 56 + 24 + (e & 31)];
    }
    __syncthreads();

    float h[16];
    const float* hp = HOUT + (((size_t)(b * DINC + dch) * NCHUNK + chunk) << 4);
#pragma unroll
    for (int n = 0; n < NST; ++n) h[n] = hp[n];

    size_t off = tokbase * DINC + dch;
    float cdt = DT[off], cu = U[off], cz = Z[off];
    for (int t = 0; t < LCHUNK; ++t) {
        float ndt = 0.f, nu = 0.f, nz = 0.f;
        if (t < LCHUNK - 1) {
            ndt = DT[off + DINC]; nu = U[off + DINC]; nz = Z[off + DINC];
        }
        const float du = cdt * cu;
        float y = 0.f;
#pragma unroll
        for (int n = 0; n < NST; ++n) {
            h[n] = __expf(cdt * Arow[n]) * h[n] + du * bcs[t][n];
            y = fmaf(h[n], bcs[t][16 + n], y);
        }
        y += cu * Dsk;
        const float sz = cz / (1.f + __expf(-cz));
        DT[off] = y * sz;
        off += DINC;
        cdt = ndt; cu = nu; cz = nz;
    }
}

// ---------------------------------------------------------------------------
extern "C" void kernel_launch(void* const* d_in, const int* in_sizes, int n_in,
                              void* d_out, int out_size, void* d_ws, size_t ws_size,
                              hipStream_t stream) {
    (void)in_sizes; (void)n_in; (void)out_size; (void)ws_size;
    const float* x         = (const float*)d_in[0];
    const float* w1        = (const float*)d_in[1];
    const float* w2        = (const float*)d_in[3];
    const float* w3        = (const float*)d_in[5];
    const float* w4        = (const float*)d_in[7];
    const float* ln_g      = (const float*)d_in[9];
    const float* ln_b      = (const float*)d_in[10];
    const float* in_proj_w = (const float*)d_in[11];
    const float* conv1d_w  = (const float*)d_in[12];
    const float* conv1d_b  = (const float*)d_in[13];
    const float* x_proj_w  = (const float*)d_in[14];
    const float* dt_proj_w = (const float*)d_in[15];
    const float* dt_proj_b = (const float*)d_in[16];
    const float* A_log     = (const float*)d_in[17];
    const float* D_skip    = (const float*)d_in[18];
    const float* out_proj_w= (const float*)d_in[19];
    float* out = (float*)d_out;

    // Workspace layout (floats). Lifetimes disjoint where regions alias.
    float* ws  = (float*)d_ws;
    float* A   = ws;                   //  6291456  [B,C,S]
    float* Bb  = ws + 6291456;         //  6291456  [B,C,S]
    float* X1  = ws + 12582912;        // 12582912  xin (conv phase: Wb+Xpad)
    float* X2  = ws + 25165824;        // 12582912  z
    float* U   = ws + 37748736;        // 12582912  u
    float* STATS = X2;
    float* DBL   = A;                  // 16384*56, after A (tn) consumed
    float* DTb   = X1;                 // dt/y, after X1 (xin) consumed
    float* HOUT  = Bb;                 // 3145728 floats (scan phase; Bb dead)
    float* SDT   = Bb + 3145728;       //  196608 floats
    ushort_t* Wb = (ushort_t*)(X1);
    ushort_t* Xp = (ushort_t*)(X1 + 2097152);
    const size_t XP_BYTES = (size_t)4 * 18 * 18 * 18 * CDIM * 2;
    const long CS = (long)CDIM * SDIM;

    const int ewGrid = (BDIM * CDIM * SDIM / 4) / 256;   // 6144

    // ---- GSC: conv1 (MFMA) -> IN -> relu
    hipMemsetAsync(Xp, 0, XP_BYTES, stream);
    wconv_kernel<<<576, 256, 0, stream>>>(w1, Wb);
    pad_kernel<<<1024, 384, 0, stream>>>(x, Xp);
    conv_mfma_kernel<<<dim3(128, 3), 256, 0, stream>>>(Xp, Wb, A);
    inorm_stats_kernel<<<1536, 256, 0, stream>>>(A, STATS);
    norm_relu_kernel<<<ewGrid, 256, 0, stream>>>(A, STATS, nullptr, A);
    // ---- conv2 (MFMA) -> IN -> relu
    wconv_kernel<<<576, 256, 0, stream>>>(w2, Wb);
    pad_kernel<<<1024, 384, 0, stream>>>(A, Xp);
    conv_mfma_kernel<<<dim3(128, 3), 256, 0, stream>>>(Xp, Wb, Bb);
    inorm_stats_kernel<<<1536, 256, 0, stream>>>(Bb, STATS);
    norm_relu_kernel<<<ewGrid, 256, 0, stream>>>(Bb, STATS, nullptr, Bb);
    // ---- conv3 (1x1) -> IN -> relu, + x1 path => A = x1+x2
    gemm_kernel<false, 0><<<dim3(64, 3, 4), 256, 0, stream>>>(
        w3, x, A, nullptr, nullptr, CDIM, SDIM, CDIM, CDIM, SDIM, SDIM, 0, CS, CS);
    inorm_stats_kernel<<<1536, 256, 0, stream>>>(A, STATS);
    norm_relu_kernel<<<ewGrid, 256, 0, stream>>>(A, STATS, Bb, A);
    // ---- conv4 (1x1) -> IN -> relu, + x residual => Bb = xg
    gemm_kernel<false, 0><<<dim3(64, 3, 4), 256, 0, stream>>>(
        w4, A, Bb, nullptr, nullptr, CDIM, SDIM, CDIM, CDIM, SDIM, SDIM, 0, CS, CS);
    inorm_stats_kernel<<<1536, 256, 0, stream>>>(Bb, STATS);
    norm_relu_kernel<<<ewGrid, 256, 0, stream>>>(Bb, STATS, x, Bb);
    // ---- LayerNorm + transpose: Bb [b][c][s] -> A = tn [b][l][c]
    layernorm_kernel<<<4096, 256, 0, stream>>>(Bb, ln_g, ln_b, A);
    // ---- in_proj -> split X1 (xin), X2 (z)
    gemm_kernel<true, 1><<<dim3(24, 128, 1), 256, 0, stream>>>(
        A, in_proj_w, X1, X2, nullptr, 16384, 1536, CDIM, CDIM, CDIM, DINC, 0, 0, 0);
    // ---- causal depthwise conv + SiLU -> U
    dwconv_silu_kernel<<<dim3(3, 4096, 4), 256, 0, stream>>>(X1, conv1d_w, conv1d_b, U);
    // ---- x_proj -> DBL [16384,56]
    gemm_kernel<true, 0><<<dim3(1, 128, 1), 256, 0, stream>>>(
        U, x_proj_w, DBL, nullptr, nullptr, 16384, 56, DINC, DINC, DINC, 56, 0, 0, 0);
    // ---- dt_proj + bias, softplus -> DTb
    gemm_kernel<true, 2><<<dim3(12, 128, 1), 256, 0, stream>>>(
        DBL, dt_proj_w, DTb, nullptr, dt_proj_b, 16384, DINC, 24, 56, 24, DINC, 0, 0, 0);
    // ---- chunked parallel selective scan (y over DTb)
    scan_phase1_kernel<<<dim3(3, NCHUNK, 4), 256, 0, stream>>>(
        DTb, U, DBL, A_log, HOUT, SDT);
    scan_phase2_kernel<<<192, 256, 0, stream>>>(HOUT, SDT, A_log);
    scan_phase3_kernel<<<dim3(3, NCHUNK, 4), 256, 0, stream>>>(
        DTb, U, DBL, X2, A_log, D_skip, HOUT);
    // ---- out_proj -> d_out (transposed store)
    gemm_kernel<true, 3><<<dim3(6, 128, 1), 256, 0, stream>>>(
        DTb, out_proj_w, out, nullptr, nullptr, 16384, CDIM, DINC, DINC, DINC, 0, 0, 0, 0);
}

// Round 4
// 1026.909 us; speedup vs baseline: 7.2944x; 1.6035x over previous
//
#include <hip/hip_runtime.h>
#include <math.h>

#define CDIM 384
#define SDIM 4096
#define BDIM 4
#define DINC 768
#define NST  16
#define NCHUNK 64
#define LCHUNK 64

typedef unsigned short ushort_t;
typedef unsigned int uint_t;
typedef __attribute__((ext_vector_type(4))) float f32x4;
typedef __attribute__((ext_vector_type(8))) short bf16x8;

__device__ __forceinline__ ushort_t f2bf(float f) {
    union { float f; uint_t u; } v; v.f = f;
    uint_t r = v.u + 0x7FFFu + ((v.u >> 16) & 1u);   // round-to-nearest-even
    return (ushort_t)(r >> 16);
}
__device__ __forceinline__ uint_t pk2(float a, float b) {
    return (uint_t)f2bf(a) | ((uint_t)f2bf(b) << 16);
}

// ---------------------------------------------------------------------------
// fp32 -> bf16 flat convert (n multiple of 4).
// ---------------------------------------------------------------------------
__global__ __launch_bounds__(256)
void cvt_bf16_kernel(const float* __restrict__ src, ushort_t* __restrict__ dst, int n4) {
    const int i = blockIdx.x * 256 + threadIdx.x;
    if (i >= n4) return;
    float4 v = ((const float4*)src)[i];
    uint2 o; o.x = pk2(v.x, v.y); o.y = pk2(v.z, v.w);
    ((uint2*)dst)[i] = o;
}

// ---------------------------------------------------------------------------
// Weight convert 3x3x3: W[co][ci][27] fp32 -> Wb[tap][co][ci] bf16.
// ---------------------------------------------------------------------------
__global__ __launch_bounds__(256)
void wconv_kernel(const float* __restrict__ W, ushort_t* __restrict__ Wb) {
    const int idx = blockIdx.x * 256 + threadIdx.x;      // co*384 + ci
    const float* wp = W + (size_t)idx * 27;
#pragma unroll
    for (int tap = 0; tap < 27; ++tap)
        Wb[(size_t)tap * (CDIM * CDIM) + idx] = f2bf(wp[tap]);
}

// ---------------------------------------------------------------------------
// Pad + transpose to channels-last bf16: src[b][c][16^3] -> Xp[b][18][18][18][384]
// ---------------------------------------------------------------------------
__global__ __launch_bounds__(384)
void pad_kernel(const float* __restrict__ src, ushort_t* __restrict__ Xp) {
    const int blk = blockIdx.x;                          // b(4) d(16) h(16)
    const int b = blk >> 8, d = (blk >> 4) & 15, h = blk & 15;
    const int ci = threadIdx.x;
    const float* sp = src + (size_t)(b * CDIM + ci) * SDIM + d * 256 + h * 16;
    ushort_t* dp = Xp + ((((size_t)(b * 18 + d + 1) * 18) + (h + 1)) * 18 + 1) * CDIM + ci;
#pragma unroll
    for (int w = 0; w < 16; ++w)
        dp[(size_t)w * CDIM] = f2bf(sp[w]);
}

// ---------------------------------------------------------------------------
// Implicit-GEMM conv via MFMA bf16 (fp32 accum). NTAP=27 (3x3x3 pad=1) or
// NTAP=1 (1x1x1 center tap). Block 128co x 128s, 4 waves 2x2, BK=32,
// double-buffered LDS, issue-early/write-late staging.
// ---------------------------------------------------------------------------
template<int NTAP>
__global__ __launch_bounds__(256)
void conv_mfma_kernel(const ushort_t* __restrict__ Xp, const ushort_t* __restrict__ Wb,
                      float* __restrict__ Y) {
    const int nt = blockIdx.x;
    const int b  = nt >> 5;
    const int d  = (nt >> 1) & 15;
    const int h0 = (nt & 1) * 8;
    const int co0 = blockIdx.y * 128;
    const int t = threadIdx.x;
    const int lane = t & 63;
    const int wid = t >> 6;
    const int wy = wid >> 1, wx = wid & 1;

    __shared__ ushort_t As[2][128 * 40];
    __shared__ ushort_t Bs[2][128 * 40];

    f32x4 acc[4][4];
#pragma unroll
    for (int i = 0; i < 4; ++i)
#pragma unroll
        for (int j = 0; j < 4; ++j) acc[i][j] = (f32x4){0.f, 0.f, 0.f, 0.f};

    const int arow = t >> 1, half = t & 1;
    const int hl = arow >> 4, w = arow & 15;
    const size_t wbase = (size_t)(co0 + arow) * CDIM + half * 16;
    const int wA = arow * 40 + half * 16;

    const int lm = lane & 15, lk = (lane >> 4) * 8;
    const int rA0 = (wy * 64 + lm) * 40 + lk;
    const int rB0 = (wx * 64 + lm) * 40 + lk;

    uint4 ra0, ra1, rb0, rb1;

    auto loadg = [&](int idx) {
        int tap, kd, kh, kw, chunk;
        if (NTAP == 1) {
            tap = 0; kd = 1; kh = 1; kw = 1; chunk = idx;
        } else {
            tap = idx / 12; chunk = idx - tap * 12;
            kd = tap / 9; const int r9 = tap - kd * 9;
            kh = r9 / 3; kw = r9 - kh * 3;
        }
        const uint4* pa = reinterpret_cast<const uint4*>(
            Wb + (size_t)tap * (CDIM * CDIM) + wbase + chunk * 32);
        ra0 = pa[0]; ra1 = pa[1];
        const size_t voff = ((((size_t)(b * 18 + d + kd) * 18) + (h0 + hl + kh)) * 18
                             + (w + kw)) * CDIM + chunk * 32 + half * 16;
        const uint4* pb = reinterpret_cast<const uint4*>(Xp + voff);
        rb0 = pb[0]; rb1 = pb[1];
    };
    auto lwrite = [&](int buf) {
        *reinterpret_cast<uint4*>(&As[buf][wA])     = ra0;
        *reinterpret_cast<uint4*>(&As[buf][wA + 8]) = ra1;
        *reinterpret_cast<uint4*>(&Bs[buf][wA])     = rb0;
        *reinterpret_cast<uint4*>(&Bs[buf][wA + 8]) = rb1;
    };

    loadg(0);
    lwrite(0);
    __syncthreads();

    int buf = 0;
    for (int idx = 0; idx < NTAP * 12; ++idx) {
        const bool more = (idx + 1) < NTAP * 12;
        if (more) loadg(idx + 1);
        bf16x8 af[4], bfr[4];
#pragma unroll
        for (int mi = 0; mi < 4; ++mi)
            af[mi] = *reinterpret_cast<const bf16x8*>(&As[buf][rA0 + mi * 16 * 40]);
#pragma unroll
        for (int ni = 0; ni < 4; ++ni)
            bfr[ni] = *reinterpret_cast<const bf16x8*>(&Bs[buf][rB0 + ni * 16 * 40]);
#pragma unroll
        for (int mi = 0; mi < 4; ++mi)
#pragma unroll
            for (int ni = 0; ni < 4; ++ni)
                acc[mi][ni] = __builtin_amdgcn_mfma_f32_16x16x32_bf16(
                    af[mi], bfr[ni], acc[mi][ni], 0, 0, 0);
        if (more) lwrite(buf ^ 1);
        __syncthreads();
        buf ^= 1;
    }

    const int coB = co0 + wy * 64 + (lane >> 4) * 4;
    const int nB  = wx * 64 + lm;
#pragma unroll
    for (int mi = 0; mi < 4; ++mi) {
#pragma unroll
        for (int ni = 0; ni < 4; ++ni) {
            const int nl = nB + ni * 16;
            const int s = d * 256 + (h0 + (nl >> 4)) * 16 + (nl & 15);
            float* yp = Y + ((size_t)b * CDIM + (coB + mi * 16)) * SDIM + s;
#pragma unroll
            for (int j = 0; j < 4; ++j)
                yp[(size_t)j * SDIM] = acc[mi][ni][j];
        }
    }
}

// ---------------------------------------------------------------------------
// bf16 MFMA GEMM, NT: C[M,N] = A[M,K] x B[N,K]^T. A is bf16 (AT=ushort_t) or
// fp32 converted-on-stage (AT=float). B (weights) pre-converted bf16.
// Tile 128x128xBK32, 4 waves. M%128==0; N masked on stage + store.
// EPI 0: plain fp32 store (ldc);  1: xz split (C=xin, C2=z, N=1536);
// EPI 2: transposed store C[b][n][l] float4 (out tensor).
// ---------------------------------------------------------------------------
template<typename AT, int EPI>
__global__ __launch_bounds__(256)
void gemm_mfma_kernel(const AT* __restrict__ A, const ushort_t* __restrict__ Bw,
                      float* __restrict__ C, float* __restrict__ C2,
                      int M, int N, int K, int ldc) {
    const int n0 = blockIdx.x * 128;
    const int m0 = blockIdx.y * 128;
    const int t = threadIdx.x;
    const int lane = t & 63;
    const int wid = t >> 6;
    const int wy = wid >> 1, wx = wid & 1;

    __shared__ ushort_t As[2][128 * 40];
    __shared__ ushort_t Bs[2][128 * 40];

    f32x4 acc[4][4];
#pragma unroll
    for (int i = 0; i < 4; ++i)
#pragma unroll
        for (int j = 0; j < 4; ++j) acc[i][j] = (f32x4){0.f, 0.f, 0.f, 0.f};

    const int arow = t >> 1, half = t & 1;
    const int wA = arow * 40 + half * 16;
    const int lm = lane & 15, lk = (lane >> 4) * 8;
    const int rA0 = (wy * 64 + lm) * 40 + lk;
    const int rB0 = (wx * 64 + lm) * 40 + lk;

    uint4 ra0, ra1, rb0, rb1;

    auto loadg = [&](int kk) {
        const int kb = kk * 32 + half * 16;
        if constexpr (sizeof(AT) == 2) {                 // bf16 A
            const uint4* pa = reinterpret_cast<const uint4*>(
                (const ushort_t*)A + (size_t)(m0 + arow) * K + kb);
            ra0 = pa[0]; ra1 = pa[1];
        } else {                                         // fp32 A, convert
            const float4* pa = reinterpret_cast<const float4*>(
                (const float*)A + (size_t)(m0 + arow) * K + kb);
            float4 f0 = pa[0], f1 = pa[1], f2 = pa[2], f3 = pa[3];
            ra0.x = pk2(f0.x, f0.y); ra0.y = pk2(f0.z, f0.w);
            ra0.z = pk2(f1.x, f1.y); ra0.w = pk2(f1.z, f1.w);
            ra1.x = pk2(f2.x, f2.y); ra1.y = pk2(f2.z, f2.w);
            ra1.z = pk2(f3.x, f3.y); ra1.w = pk2(f3.z, f3.w);
        }
        if (n0 + arow < N) {
            const uint4* pb = reinterpret_cast<const uint4*>(
                Bw + (size_t)(n0 + arow) * K + kb);
            rb0 = pb[0]; rb1 = pb[1];
        } else {
            rb0 = make_uint4(0, 0, 0, 0); rb1 = rb0;
        }
    };
    auto lwrite = [&](int buf) {
        *reinterpret_cast<uint4*>(&As[buf][wA])     = ra0;
        *reinterpret_cast<uint4*>(&As[buf][wA + 8]) = ra1;
        *reinterpret_cast<uint4*>(&Bs[buf][wA])     = rb0;
        *reinterpret_cast<uint4*>(&Bs[buf][wA + 8]) = rb1;
    };

    const int KI = K >> 5;
    loadg(0);
    lwrite(0);
    __syncthreads();

    int buf = 0;
    for (int kk = 0; kk < KI; ++kk) {
        const bool more = (kk + 1) < KI;
        if (more) loadg(kk + 1);
        bf16x8 af[4], bfr[4];
#pragma unroll
        for (int mi = 0; mi < 4; ++mi)
            af[mi] = *reinterpret_cast<const bf16x8*>(&As[buf][rA0 + mi * 16 * 40]);
#pragma unroll
        for (int ni = 0; ni < 4; ++ni)
            bfr[ni] = *reinterpret_cast<const bf16x8*>(&Bs[buf][rB0 + ni * 16 * 40]);
#pragma unroll
        for (int mi = 0; mi < 4; ++mi)
#pragma unroll
            for (int ni = 0; ni < 4; ++ni)
                acc[mi][ni] = __builtin_amdgcn_mfma_f32_16x16x32_bf16(
                    af[mi], bfr[ni], acc[mi][ni], 0, 0, 0);
        if (more) lwrite(buf ^ 1);
        __syncthreads();
        buf ^= 1;
    }

    const int mB = m0 + wy * 64 + (lane >> 4) * 4;
    const int nB = n0 + wx * 64 + lm;
#pragma unroll
    for (int mi = 0; mi < 4; ++mi) {
#pragma unroll
        for (int ni = 0; ni < 4; ++ni) {
            const int n = nB + ni * 16;
            if (EPI == 2) {                              // transposed float4
                const int mrow = mB + mi * 16;
                const int bb = mrow >> 12, l = mrow & 4095;
                float4 st = {acc[mi][ni][0], acc[mi][ni][1],
                             acc[mi][ni][2], acc[mi][ni][3]};
                *reinterpret_cast<float4*>(
                    C + ((size_t)(bb * CDIM + n)) * SDIM + l) = st;
            } else {
#pragma unroll
                for (int j = 0; j < 4; ++j) {
                    const int m = mB + mi * 16 + j;
                    const float v = acc[mi][ni][j];
                    if (EPI == 0) {
                        if (n < N) C[(size_t)m * ldc + n] = v;
                    } else {                             // xz split
                        if (n < DINC) C[(size_t)m * DINC + n] = v;
                        else          C2[(size_t)m * DINC + (n - DINC)] = v;
                    }
                }
            }
        }
    }
}

// ---------------------------------------------------------------------------
// InstanceNorm stats: one block per (b,c).
// ---------------------------------------------------------------------------
__global__ __launch_bounds__(256)
void inorm_stats_kernel(const float* __restrict__ X, float* __restrict__ stats) {
    const int bc = blockIdx.x;
    const float* xp = X + (size_t)bc * SDIM;
    float s = 0.f, ss = 0.f;
    for (int i = threadIdx.x * 4; i < SDIM; i += 1024) {
        float4 v = *(const float4*)(xp + i);
        s += v.x + v.y + v.z + v.w;
        ss += v.x * v.x + v.y * v.y + v.z * v.z + v.w * v.w;
    }
#pragma unroll
    for (int off = 32; off > 0; off >>= 1) {
        s += __shfl_down(s, off);
        ss += __shfl_down(ss, off);
    }
    __shared__ float rs[4], rss[4];
    const int wid = threadIdx.x >> 6;
    if ((threadIdx.x & 63) == 0) { rs[wid] = s; rss[wid] = ss; }
    __syncthreads();
    if (threadIdx.x == 0) {
        float S = rs[0] + rs[1] + rs[2] + rs[3];
        float SS = rss[0] + rss[1] + rss[2] + rss[3];
        float m = S * (1.f / SDIM);
        float var = SS * (1.f / SDIM) - m * m;
        stats[bc * 2] = m;
        stats[bc * 2 + 1] = rsqrtf(var + 1e-5f);
    }
}

// ---------------------------------------------------------------------------
// y = relu((x-m)*rstd) [+ res]
// ---------------------------------------------------------------------------
__global__ __launch_bounds__(256)
void norm_relu_kernel(const float* __restrict__ X, const float* __restrict__ stats,
                      const float* __restrict__ Res, float* __restrict__ Out) {
    const size_t idx = (size_t)blockIdx.x * 256 + threadIdx.x;
    const size_t i4 = idx * 4;
    const int bc = (int)(i4 >> 12);
    const float m = stats[bc * 2], r = stats[bc * 2 + 1];
    float4 v = *(const float4*)(X + i4);
    float4 o;
    o.x = fmaxf((v.x - m) * r, 0.f);
    o.y = fmaxf((v.y - m) * r, 0.f);
    o.z = fmaxf((v.z - m) * r, 0.f);
    o.w = fmaxf((v.w - m) * r, 0.f);
    if (Res) {
        float4 q = *(const float4*)(Res + i4);
        o.x += q.x; o.y += q.y; o.z += q.z; o.w += q.w;
    }
    *(float4*)(Out + i4) = o;
}

// ---------------------------------------------------------------------------
// LayerNorm over C with transpose: xg [b][c][s] -> tn [b][l][c] (bf16).
// ---------------------------------------------------------------------------
__global__ __launch_bounds__(256)
void layernorm_kernel(const float* __restrict__ Xg, const float* __restrict__ gam,
                      const float* __restrict__ bet, ushort_t* __restrict__ Tn) {
    const int token = blockIdx.x * 4 + (threadIdx.x >> 6);
    const int lane = threadIdx.x & 63;
    const int b = token >> 12, l = token & 4095;
    const float* xp = Xg + (size_t)b * CDIM * SDIM + l;
    float v[6];
    float s = 0.f, ss = 0.f;
#pragma unroll
    for (int i = 0; i < 6; ++i) {
        v[i] = xp[(size_t)(lane + i * 64) * SDIM];
        s += v[i]; ss += v[i] * v[i];
    }
#pragma unroll
    for (int off = 32; off > 0; off >>= 1) {
        s += __shfl_down(s, off);
        ss += __shfl_down(ss, off);
    }
    s = __shfl(s, 0); ss = __shfl(ss, 0);
    const float m = s * (1.f / CDIM);
    const float r = rsqrtf(ss * (1.f / CDIM) - m * m + 1e-5f);
    ushort_t* tp = Tn + (size_t)token * CDIM;
#pragma unroll
    for (int i = 0; i < 6; ++i) {
        const int c = lane + i * 64;
        tp[c] = f2bf((v[i] - m) * r * gam[c] + bet[c]);
    }
}

// ---------------------------------------------------------------------------
// Tiled fp32 GEMM (kept only for dt_proj, K=24). NT, EPI2 = bias+softplus.
// ---------------------------------------------------------------------------
__global__ __launch_bounds__(256)
void gemm_dtproj_kernel(const float* __restrict__ A, const float* __restrict__ B,
                        float* __restrict__ C, const float* __restrict__ bias,
                        int M, int N, int K, int lda, int ldb, int ldc) {
    __shared__ __align__(16) float As[16][132];
    __shared__ __align__(16) float Bs[16][68];
    const int t = threadIdx.x;
    const int m0 = blockIdx.y * 128;
    const int n0 = blockIdx.x * 64;

    float acc[8][4];
#pragma unroll
    for (int i = 0; i < 8; ++i)
#pragma unroll
        for (int j = 0; j < 4; ++j) acc[i][j] = 0.f;

    const int mr = (t & 15) * 8;
    const int nr = (t >> 4) * 4;

    for (int k0 = 0; k0 < K; k0 += 16) {
#pragma unroll
        for (int idx = 0; idx < 8; ++idx) {
            const int e = idx * 256 + t;
            const int k = e & 15, m = e >> 4;
            float v = 0.f;
            if (k0 + k < K) v = A[(size_t)(m0 + m) * lda + (k0 + k)];
            As[k][m] = v;
        }
#pragma unroll
        for (int idx = 0; idx < 4; ++idx) {
            const int e = idx * 256 + t;
            const int k = e & 15, n = e >> 4;
            float v = 0.f;
            if ((n0 + n) < N && (k0 + k) < K) v = B[(size_t)(n0 + n) * ldb + (k0 + k)];
            Bs[k][n] = v;
        }
        __syncthreads();
#pragma unroll
        for (int k = 0; k < 16; ++k) {
            float4 a0 = *(const float4*)&As[k][mr];
            float4 a1 = *(const float4*)&As[k][mr + 4];
            float4 b0 = *(const float4*)&Bs[k][nr];
            const float av[8] = {a0.x, a0.y, a0.z, a0.w, a1.x, a1.y, a1.z, a1.w};
            const float bv[4] = {b0.x, b0.y, b0.z, b0.w};
#pragma unroll
            for (int i = 0; i < 8; ++i)
#pragma unroll
                for (int j = 0; j < 4; ++j)
                    acc[i][j] = fmaf(av[i], bv[j], acc[i][j]);
        }
        __syncthreads();
    }

#pragma unroll
    for (int i = 0; i < 8; ++i) {
        const int m = m0 + mr + i;
#pragma unroll
        for (int j = 0; j < 4; ++j) {
            const int n = n0 + nr + j;
            if (n >= N) continue;
            float v = acc[i][j] + bias[n];
            v = (v > 20.f) ? v : log1pf(__expf(v));
            C[(size_t)m * ldc + n] = v;
        }
    }
}

// ---------------------------------------------------------------------------
// Causal depthwise conv1d (K=4) + bias + SiLU.
// ---------------------------------------------------------------------------
__global__ __launch_bounds__(256)
void dwconv_silu_kernel(const float* __restrict__ Xin, const float* __restrict__ W,
                        const float* __restrict__ bias, float* __restrict__ U) {
    const int dch = blockIdx.x * 256 + threadIdx.x;
    const int l = blockIdx.y, b = blockIdx.z;
    const float4 w4 = ((const float4*)W)[dch];
    const float wk[4] = {w4.x, w4.y, w4.z, w4.w};
    const float* xp = Xin + ((size_t)b * 4096 + l) * DINC + dch;
    float acc = bias[dch];
#pragma unroll
    for (int k = 0; k < 4; ++k) {
        const int ll = l - 3 + k;
        if (ll >= 0) acc = fmaf(xp[(k - 3) * DINC], wk[k], acc);
    }
    U[((size_t)b * 4096 + l) * DINC + dch] = acc / (1.f + __expf(-acc));
}

// ---------------------------------------------------------------------------
// Chunked parallel selective scan (3 phases), unchanged from round 3.
// ---------------------------------------------------------------------------
__global__ __launch_bounds__(256)
void scan_phase1_kernel(const float* __restrict__ DT, const float* __restrict__ U,
                        const float* __restrict__ DBL, const float* __restrict__ A_log,
                        float* __restrict__ HOUT, float* __restrict__ SDT) {
    const int b = blockIdx.z, chunk = blockIdx.y;
    const int dch = blockIdx.x * 256 + threadIdx.x;
    float Arow[16];
#pragma unroll
    for (int n = 0; n < NST; ++n) Arow[n] = -__expf(A_log[dch * NST + n]);

    __shared__ float bcs[LCHUNK][16];
    const size_t tokbase = (size_t)b * 4096 + chunk * LCHUNK;
#pragma unroll
    for (int idx = 0; idx < 4; ++idx) {
        const int e = idx * 256 + threadIdx.x;
        bcs[e >> 4][e & 15] = DBL[(tokbase + (e >> 4)) * 56 + 24 + (e & 15)];
    }
    __syncthreads();

    size_t off = tokbase * DINC + dch;
    float h[16];
#pragma unroll
    for (int n = 0; n < NST; ++n) h[n] = 0.f;
    float sdt = 0.f;
    float cdt = DT[off], cu = U[off];
    for (int t = 0; t < LCHUNK; ++t) {
        float ndt = 0.f, nu = 0.f;
        if (t < LCHUNK - 1) { ndt = DT[off + DINC]; nu = U[off + DINC]; }
        sdt += cdt;
        const float du = cdt * cu;
#pragma unroll
        for (int n = 0; n < NST; ++n)
            h[n] = __expf(cdt * Arow[n]) * h[n] + du * bcs[t][n];
        off += DINC;
        cdt = ndt; cu = nu;
    }
    float* hp = HOUT + (((size_t)(b * DINC + dch) * NCHUNK + chunk) << 4);
#pragma unroll
    for (int n = 0; n < NST; ++n) hp[n] = h[n];
    SDT[(size_t)(b * DINC + dch) * NCHUNK + chunk] = sdt;
}

__global__ __launch_bounds__(256)
void scan_phase2_kernel(float* __restrict__ HOUT, const float* __restrict__ SDT,
                        const float* __restrict__ A_log) {
    const int t = blockIdx.x * 256 + threadIdx.x;        // 49152
    const int b = t / (DINC * NST);
    const int rem = t - b * (DINC * NST);
    const int d = rem >> 4, n = rem & 15;
    const float An = -__expf(A_log[d * NST + n]);
    float* hp = HOUT + (((size_t)(b * DINC + d) * NCHUNK) << 4) + n;
    const float* sp = SDT + (size_t)(b * DINC + d) * NCHUNK;
    float H = 0.f;
    for (int c = 0; c < NCHUNK; ++c) {
        const float tmp = hp[c * 16];
        const float dA = __expf(An * sp[c]);
        hp[c * 16] = H;
        H = dA * H + tmp;
    }
}

__global__ __launch_bounds__(256)
void scan_phase3_kernel(float* __restrict__ DT, const float* __restrict__ U,
                        const float* __restrict__ DBL, const float* __restrict__ Z,
                        const float* __restrict__ A_log, const float* __restrict__ D_skip,
                        const float* __restrict__ HOUT) {
    const int b = blockIdx.z, chunk = blockIdx.y;
    const int dch = blockIdx.x * 256 + threadIdx.x;
    float Arow[16];
#pragma unroll
    for (int n = 0; n < NST; ++n) Arow[n] = -__expf(A_log[dch * NST + n]);
    const float Dsk = D_skip[dch];

    __shared__ float bcs[LCHUNK][32];
    const size_t tokbase = (size_t)b * 4096 + chunk * LCHUNK;
#pragma unroll
    for (int idx = 0; idx < 8; ++idx) {
        const int e = idx * 256 + threadIdx.x;
        bcs[e >> 5][e & 31] = DBL[(tokbase + (e >> 5)) * 56 + 24 + (e & 31)];
    }
    __syncthreads();

    float h[16];
    const float* hp = HOUT + (((size_t)(b * DINC + dch) * NCHUNK + chunk) << 4);
#pragma unroll
    for (int n = 0; n < NST; ++n) h[n] = hp[n];

    size_t off = tokbase * DINC + dch;
    float cdt = DT[off], cu = U[off], cz = Z[off];
    for (int t = 0; t < LCHUNK; ++t) {
        float ndt = 0.f, nu = 0.f, nz = 0.f;
        if (t < LCHUNK - 1) {
            ndt = DT[off + DINC]; nu = U[off + DINC]; nz = Z[off + DINC];
        }
        const float du = cdt * cu;
        float y = 0.f;
#pragma unroll
        for (int n = 0; n < NST; ++n) {
            h[n] = __expf(cdt * Arow[n]) * h[n] + du * bcs[t][n];
            y = fmaf(h[n], bcs[t][16 + n], y);
        }
        y += cu * Dsk;
        const float sz = cz / (1.f + __expf(-cz));
        DT[off] = y * sz;
        off += DINC;
        cdt = ndt; cu = nu; cz = nz;
    }
}

// ---------------------------------------------------------------------------
extern "C" void kernel_launch(void* const* d_in, const int* in_sizes, int n_in,
                              void* d_out, int out_size, void* d_ws, size_t ws_size,
                              hipStream_t stream) {
    (void)in_sizes; (void)n_in; (void)out_size; (void)ws_size;
    const float* x         = (const float*)d_in[0];
    const float* w1        = (const float*)d_in[1];
    const float* w2        = (const float*)d_in[3];
    const float* w3        = (const float*)d_in[5];
    const float* w4        = (const float*)d_in[7];
    const float* ln_g      = (const float*)d_in[9];
    const float* ln_b      = (const float*)d_in[10];
    const float* in_proj_w = (const float*)d_in[11];
    const float* conv1d_w  = (const float*)d_in[12];
    const float* conv1d_b  = (const float*)d_in[13];
    const float* x_proj_w  = (const float*)d_in[14];
    const float* dt_proj_w = (const float*)d_in[15];
    const float* dt_proj_b = (const float*)d_in[16];
    const float* A_log     = (const float*)d_in[17];
    const float* D_skip    = (const float*)d_in[18];
    const float* out_proj_w= (const float*)d_in[19];
    float* out = (float*)d_out;

    // Workspace regions (floats): R0..R4. Lifetimes disjoint where aliased.
    float* ws = (float*)d_ws;
    float* R0 = ws;                    //  6291456
    float* R1 = ws + 6291456;          //  6291456
    float* R2 = ws + 12582912;         // 12582912
    float* R3 = ws + 25165824;         // 12582912
    float* R4 = ws + 37748736;         // 12582912

    // GSC-phase aliases
    ushort_t* Wb27 = (ushort_t*)R2;                  // 3981312 bf16
    ushort_t* Xp   = (ushort_t*)(R2 + 2097152);      // 8957952 bf16
    ushort_t* w3b  = (ushort_t*)(R2 + 6576128);      // 147456 bf16
    ushort_t* w4b  = (ushort_t*)(R2 + 6649856);      // 147456 bf16
    float*    STATS = R4;                            // 3072 floats
    // Mamba-phase aliases
    ushort_t* tnb   = (ushort_t*)R0;                 // 16384*384 bf16
    float*    DBL   = R0 + 3145728;                  // 16384*56
    ushort_t* ipwb  = (ushort_t*)R1;                 // 1536*384 bf16
    ushort_t* opwb  = (ushort_t*)(R1 + 294912);      // 384*768 bf16
    ushort_t* xpwb  = (ushort_t*)(R1 + 442368);      // 56*768 bf16 (21504 fl)
    float*    HOUT  = R1 + 463872;                   // 3145728
    float*    SDT   = R1 + 3609600;                  // 196608 -> 3806208 OK
    float*    XIN   = R2;                            // 16384*768 (over Wb/Xp)
    float*    Zb    = R3;                            // 16384*768
    float*    Ub    = R4;                            // 16384*768
    float*    DTb   = R2;                            // dt/y over XIN

    const size_t XP_BYTES = (size_t)4 * 18 * 18 * 18 * CDIM * 2;
    const int ewGrid = (BDIM * CDIM * SDIM / 4) / 256;   // 6144
    const dim3 cgrid(128, 3);

    // ---- GSC block ----
    hipMemsetAsync(Xp, 0, XP_BYTES, stream);             // zero pad borders
    pad_kernel<<<1024, 384, 0, stream>>>(x, Xp);         // x channels-last
    wconv_kernel<<<576, 256, 0, stream>>>(w1, Wb27);
    conv_mfma_kernel<27><<<cgrid, 256, 0, stream>>>(Xp, Wb27, R0);   // c1
    cvt_bf16_kernel<<<144, 256, 0, stream>>>(w3, w3b, 36864);
    conv_mfma_kernel<1><<<cgrid, 256, 0, stream>>>(Xp, w3b, R3);     // c3 (from x)
    inorm_stats_kernel<<<1536, 256, 0, stream>>>(R0, STATS);
    norm_relu_kernel<<<ewGrid, 256, 0, stream>>>(R0, STATS, nullptr, R0); // x1a
    pad_kernel<<<1024, 384, 0, stream>>>(R0, Xp);        // x1a channels-last
    wconv_kernel<<<576, 256, 0, stream>>>(w2, Wb27);
    conv_mfma_kernel<27><<<cgrid, 256, 0, stream>>>(Xp, Wb27, R1);   // c2
    inorm_stats_kernel<<<1536, 256, 0, stream>>>(R1, STATS);
    norm_relu_kernel<<<ewGrid, 256, 0, stream>>>(R1, STATS, nullptr, R1); // x1
    inorm_stats_kernel<<<1536, 256, 0, stream>>>(R3, STATS);
    norm_relu_kernel<<<ewGrid, 256, 0, stream>>>(R3, STATS, R1, R0); // S=x1+x2
    pad_kernel<<<1024, 384, 0, stream>>>(R0, Xp);        // S channels-last
    cvt_bf16_kernel<<<144, 256, 0, stream>>>(w4, w4b, 36864);
    conv_mfma_kernel<1><<<cgrid, 256, 0, stream>>>(Xp, w4b, R3);     // c4
    inorm_stats_kernel<<<1536, 256, 0, stream>>>(R3, STATS);
    norm_relu_kernel<<<ewGrid, 256, 0, stream>>>(R3, STATS, x, R1);  // xg
    // ---- LayerNorm -> tn bf16 [b][l][c]
    layernorm_kernel<<<4096, 256, 0, stream>>>(R1, ln_g, ln_b, tnb);
    // ---- weight converts (R1 dead now)
    cvt_bf16_kernel<<<576, 256, 0, stream>>>(in_proj_w, ipwb, 147456);
    cvt_bf16_kernel<<<288, 256, 0, stream>>>(out_proj_w, opwb, 73728);
    cvt_bf16_kernel<<<42, 256, 0, stream>>>(x_proj_w, xpwb, 10752);
    // ---- in_proj (bf16 MFMA): tn x W^T -> split XIN | Zb
    gemm_mfma_kernel<ushort_t, 1><<<dim3(12, 128), 256, 0, stream>>>(
        tnb, ipwb, XIN, Zb, 16384, 1536, CDIM, 0);
    // ---- causal depthwise conv + SiLU -> Ub
    dwconv_silu_kernel<<<dim3(3, 4096, 4), 256, 0, stream>>>(XIN, conv1d_w, conv1d_b, Ub);
    // ---- x_proj (bf16 MFMA, N=56 masked): u x W^T -> DBL
    gemm_mfma_kernel<float, 0><<<dim3(1, 128), 256, 0, stream>>>(
        Ub, xpwb, DBL, nullptr, 16384, 56, DINC, 56);
    // ---- dt_proj (fp32, K=24) + bias + softplus -> DTb (over XIN)
    gemm_dtproj_kernel<<<dim3(12, 128), 256, 0, stream>>>(
        DBL, dt_proj_w, DTb, dt_proj_b, 16384, DINC, 24, 56, 24, DINC);
    // ---- chunked parallel selective scan (y over DTb, fp32)
    scan_phase1_kernel<<<dim3(3, NCHUNK, 4), 256, 0, stream>>>(
        DTb, Ub, DBL, A_log, HOUT, SDT);
    scan_phase2_kernel<<<192, 256, 0, stream>>>(HOUT, SDT, A_log);
    scan_phase3_kernel<<<dim3(3, NCHUNK, 4), 256, 0, stream>>>(
        DTb, Ub, DBL, Zb, A_log, D_skip, HOUT);
    // ---- out_proj (bf16 MFMA, fp32-A converting loader) -> d_out transposed
    gemm_mfma_kernel<float, 2><<<dim3(3, 128), 256, 0, stream>>>(
        DTb, opwb, out, nullptr, 16384, CDIM, DINC, 0);
}

// Round 5
// 903.938 us; speedup vs baseline: 8.2867x; 1.1360x over previous
//
#include <hip/hip_runtime.h>
#include <math.h>

#define CDIM 384
#define SDIM 4096
#define BDIM 4
#define DINC 768
#define NST  16
#define NCHUNK 64
#define LCHUNK 64
#define PSTRIDE 6291456   // floats per conv partial [B,C,S]

typedef unsigned short ushort_t;
typedef unsigned int uint_t;
typedef __attribute__((ext_vector_type(4))) float f32x4;
typedef __attribute__((ext_vector_type(8))) short bf16x8;

__device__ __forceinline__ ushort_t f2bf(float f) {
    union { float f; uint_t u; } v; v.f = f;
    uint_t r = v.u + 0x7FFFu + ((v.u >> 16) & 1u);   // round-to-nearest-even
    return (ushort_t)(r >> 16);
}
__device__ __forceinline__ uint_t pk2(float a, float b) {
    return (uint_t)f2bf(a) | ((uint_t)f2bf(b) << 16);
}

// ---------------------------------------------------------------------------
// fp32 -> bf16 flat convert (n4 = n/4).
// ---------------------------------------------------------------------------
__global__ __launch_bounds__(256)
void cvt_bf16_kernel(const float* __restrict__ src, ushort_t* __restrict__ dst, int n4) {
    const int i = blockIdx.x * 256 + threadIdx.x;
    if (i >= n4) return;
    float4 v = ((const float4*)src)[i];
    uint2 o; o.x = pk2(v.x, v.y); o.y = pk2(v.z, v.w);
    ((uint2*)dst)[i] = o;
}

// ---------------------------------------------------------------------------
// Weight convert 3x3x3: W[co][ci][27] fp32 -> Wb[tap][co][ci] bf16.
// ---------------------------------------------------------------------------
__global__ __launch_bounds__(256)
void wconv_kernel(const float* __restrict__ W, ushort_t* __restrict__ Wb) {
    const int idx = blockIdx.x * 256 + threadIdx.x;      // co*384 + ci
    const float* wp = W + (size_t)idx * 27;
#pragma unroll
    for (int tap = 0; tap < 27; ++tap)
        Wb[(size_t)tap * (CDIM * CDIM) + idx] = f2bf(wp[tap]);
}

// ---------------------------------------------------------------------------
// Pad + transpose to channels-last bf16: src[b][c][16^3] -> Xp[b][18][18][18][384]
// ---------------------------------------------------------------------------
__global__ __launch_bounds__(384)
void pad_kernel(const float* __restrict__ src, ushort_t* __restrict__ Xp) {
    const int blk = blockIdx.x;                          // b(4) d(16) h(16)
    const int b = blk >> 8, d = (blk >> 4) & 15, h = blk & 15;
    const int ci = threadIdx.x;
    const float* sp = src + (size_t)(b * CDIM + ci) * SDIM + d * 256 + h * 16;
    ushort_t* dp = Xp + ((((size_t)(b * 18 + d + 1) * 18) + (h + 1)) * 18 + 1) * CDIM + ci;
#pragma unroll
    for (int w = 0; w < 16; ++w)
        dp[(size_t)w * CDIM] = f2bf(sp[w]);
}

// ---------------------------------------------------------------------------
// Fused: v = relu((P0+P1 - m)*r) -> pad/transpose to channels-last bf16 Xp.
// ---------------------------------------------------------------------------
__global__ __launch_bounds__(384)
void pad_fuse2_kernel(const float* __restrict__ P0, const float* __restrict__ P1,
                      const float* __restrict__ stats, ushort_t* __restrict__ Xp) {
    const int blk = blockIdx.x;
    const int b = blk >> 8, d = (blk >> 4) & 15, h = blk & 15;
    const int ci = threadIdx.x;
    const size_t o = (size_t)(b * CDIM + ci) * SDIM + d * 256 + h * 16;
    const float m = stats[(b * CDIM + ci) * 2], r = stats[(b * CDIM + ci) * 2 + 1];
    ushort_t* dp = Xp + ((((size_t)(b * 18 + d + 1) * 18) + (h + 1)) * 18 + 1) * CDIM + ci;
#pragma unroll
    for (int w = 0; w < 16; ++w) {
        const float v = P0[o + w] + P1[o + w];
        dp[(size_t)w * CDIM] = f2bf(fmaxf((v - m) * r, 0.f));
    }
}

// ---------------------------------------------------------------------------
// Fused: S = relu((P0+P1-m2)*r2) + relu((C3-m3)*r3) -> pad channels-last bf16.
// ---------------------------------------------------------------------------
__global__ __launch_bounds__(384)
void pad_fuse3_kernel(const float* __restrict__ P0, const float* __restrict__ P1,
                      const float* __restrict__ st2, const float* __restrict__ C3,
                      const float* __restrict__ st3, ushort_t* __restrict__ Xp) {
    const int blk = blockIdx.x;
    const int b = blk >> 8, d = (blk >> 4) & 15, h = blk & 15;
    const int ci = threadIdx.x;
    const size_t o = (size_t)(b * CDIM + ci) * SDIM + d * 256 + h * 16;
    const float m2 = st2[(b * CDIM + ci) * 2], r2 = st2[(b * CDIM + ci) * 2 + 1];
    const float m3 = st3[(b * CDIM + ci) * 2], r3 = st3[(b * CDIM + ci) * 2 + 1];
    ushort_t* dp = Xp + ((((size_t)(b * 18 + d + 1) * 18) + (h + 1)) * 18 + 1) * CDIM + ci;
#pragma unroll
    for (int w = 0; w < 16; ++w) {
        const float x1 = fmaxf((P0[o + w] + P1[o + w] - m2) * r2, 0.f);
        const float x2 = fmaxf((C3[o + w] - m3) * r3, 0.f);
        dp[(size_t)w * CDIM] = f2bf(x1 + x2);
    }
}

// ---------------------------------------------------------------------------
// Implicit-GEMM conv via MFMA bf16 (fp32 accum). NTAP=27 with NSPLIT=2 K-split
// over taps (z=0: 0..13, z=1: 14..26 -> partials Y+z*PSTRIDE), or NTAP=1
// (1x1x1 center tap, no split). Block 128co x 128s, 4 waves 2x2, BK=32,
// double-buffered LDS, issue-early/write-late staging. Inner loop uses
// incremental pointer walking (no divides).
// ---------------------------------------------------------------------------
template<int NTAP, int NSPLIT>
__global__ __launch_bounds__(256)
void conv_mfma_kernel(const ushort_t* __restrict__ Xp, const ushort_t* __restrict__ Wb,
                      float* __restrict__ Y) {
    const int nt = blockIdx.x;
    const int b  = nt >> 5;
    const int d  = (nt >> 1) & 15;
    const int h0 = (nt & 1) * 8;
    const int co0 = blockIdx.y * 128;
    const int t = threadIdx.x;
    const int lane = t & 63;
    const int wid = t >> 6;
    const int wy = wid >> 1, wx = wid & 1;

    int tap0, iters, kd0, kh0, kw0;
    if (NTAP == 1) {
        tap0 = 0; iters = 12; kd0 = 1; kh0 = 1; kw0 = 1;
    } else if (NSPLIT == 2) {
        const int z = blockIdx.z;
        tap0 = z ? 14 : 0; iters = (z ? 13 : 14) * 12;
        kd0 = z ? 1 : 0; kh0 = z ? 1 : 0; kw0 = z ? 2 : 0;
        Y += (size_t)z * PSTRIDE;
    } else {
        tap0 = 0; iters = 27 * 12; kd0 = kh0 = kw0 = 0;
    }

    __shared__ ushort_t As[2][128 * 40];
    __shared__ ushort_t Bs[2][128 * 40];

    f32x4 acc[4][4];
#pragma unroll
    for (int i = 0; i < 4; ++i)
#pragma unroll
        for (int j = 0; j < 4; ++j) acc[i][j] = (f32x4){0.f, 0.f, 0.f, 0.f};

    const int arow = t >> 1, half = t & 1;
    const int hl = arow >> 4, w = arow & 15;
    const int wA = arow * 40 + half * 16;

    const int lm = lane & 15, lk = (lane >> 4) * 8;
    const int rA0 = (wy * 64 + lm) * 40 + lk;
    const int rB0 = (wx * 64 + lm) * 40 + lk;

    // incremental pointers: +32/iter; A +147072 per tap wrap; B +5760 on kh
    // wrap, +109440 on kd wrap (kw wraps are seamless: 12*32 == CDIM).
    const ushort_t* ap = Wb + (size_t)tap0 * (CDIM * CDIM)
                       + (size_t)(co0 + arow) * CDIM + half * 16;
    const ushort_t* bp = Xp + ((((size_t)(b * 18 + d + kd0) * 18) + (h0 + hl + kh0)) * 18
                               + (w + kw0)) * CDIM + half * 16;
    int c12 = 0, ckw = kw0, ckh = kh0;

    uint4 ra0, ra1, rb0, rb1;

    auto loadg = [&]() {
        const uint4* pa = reinterpret_cast<const uint4*>(ap);
        ra0 = pa[0]; ra1 = pa[1];
        const uint4* pb = reinterpret_cast<const uint4*>(bp);
        rb0 = pb[0]; rb1 = pb[1];
        ap += 32; bp += 32;
        if (++c12 == 12) {
            c12 = 0;
            ap += CDIM * CDIM - 384;
            if (++ckw == 3) {
                ckw = 0;
                if (++ckh == 3) { ckh = 0; bp += 109440; }
                else bp += 5760;
            }
        }
    };
    auto lwrite = [&](int buf) {
        *reinterpret_cast<uint4*>(&As[buf][wA])     = ra0;
        *reinterpret_cast<uint4*>(&As[buf][wA + 8]) = ra1;
        *reinterpret_cast<uint4*>(&Bs[buf][wA])     = rb0;
        *reinterpret_cast<uint4*>(&Bs[buf][wA + 8]) = rb1;
    };

    loadg();
    lwrite(0);
    __syncthreads();

    int buf = 0;
    for (int idx = 0; idx < iters; ++idx) {
        const bool more = (idx + 1) < iters;
        if (more) loadg();                               // issue early
        bf16x8 af[4], bfr[4];
#pragma unroll
        for (int mi = 0; mi < 4; ++mi)
            af[mi] = *reinterpret_cast<const bf16x8*>(&As[buf][rA0 + mi * 16 * 40]);
#pragma unroll
        for (int ni = 0; ni < 4; ++ni)
            bfr[ni] = *reinterpret_cast<const bf16x8*>(&Bs[buf][rB0 + ni * 16 * 40]);
#pragma unroll
        for (int mi = 0; mi < 4; ++mi)
#pragma unroll
            for (int ni = 0; ni < 4; ++ni)
                acc[mi][ni] = __builtin_amdgcn_mfma_f32_16x16x32_bf16(
                    af[mi], bfr[ni], acc[mi][ni], 0, 0, 0);
        if (more) lwrite(buf ^ 1);                       // write late
        __syncthreads();
        buf ^= 1;
    }

    const int coB = co0 + wy * 64 + (lane >> 4) * 4;
    const int nB  = wx * 64 + lm;
#pragma unroll
    for (int mi = 0; mi < 4; ++mi) {
#pragma unroll
        for (int ni = 0; ni < 4; ++ni) {
            const int nl = nB + ni * 16;
            const int s = d * 256 + (h0 + (nl >> 4)) * 16 + (nl & 15);
            float* yp = Y + ((size_t)b * CDIM + (coB + mi * 16)) * SDIM + s;
#pragma unroll
            for (int j = 0; j < 4; ++j)
                yp[(size_t)j * SDIM] = acc[mi][ni][j];
        }
    }
}

// ---------------------------------------------------------------------------
// bf16 MFMA GEMM, NT: C[M,N] = A[M,K] x B[N,K]^T. (unchanged from round 4)
// ---------------------------------------------------------------------------
template<typename AT, int EPI>
__global__ __launch_bounds__(256)
void gemm_mfma_kernel(const AT* __restrict__ A, const ushort_t* __restrict__ Bw,
                      float* __restrict__ C, float* __restrict__ C2,
                      int M, int N, int K, int ldc) {
    const int n0 = blockIdx.x * 128;
    const int m0 = blockIdx.y * 128;
    const int t = threadIdx.x;
    const int lane = t & 63;
    const int wid = t >> 6;
    const int wy = wid >> 1, wx = wid & 1;

    __shared__ ushort_t As[2][128 * 40];
    __shared__ ushort_t Bs[2][128 * 40];

    f32x4 acc[4][4];
#pragma unroll
    for (int i = 0; i < 4; ++i)
#pragma unroll
        for (int j = 0; j < 4; ++j) acc[i][j] = (f32x4){0.f, 0.f, 0.f, 0.f};

    const int arow = t >> 1, half = t & 1;
    const int wA = arow * 40 + half * 16;
    const int lm = lane & 15, lk = (lane >> 4) * 8;
    const int rA0 = (wy * 64 + lm) * 40 + lk;
    const int rB0 = (wx * 64 + lm) * 40 + lk;

    uint4 ra0, ra1, rb0, rb1;

    auto loadg = [&](int kk) {
        const int kb = kk * 32 + half * 16;
        if constexpr (sizeof(AT) == 2) {                 // bf16 A
            const uint4* pa = reinterpret_cast<const uint4*>(
                (const ushort_t*)A + (size_t)(m0 + arow) * K + kb);
            ra0 = pa[0]; ra1 = pa[1];
        } else {                                         // fp32 A, convert
            const float4* pa = reinterpret_cast<const float4*>(
                (const float*)A + (size_t)(m0 + arow) * K + kb);
            float4 f0 = pa[0], f1 = pa[1], f2 = pa[2], f3 = pa[3];
            ra0.x = pk2(f0.x, f0.y); ra0.y = pk2(f0.z, f0.w);
            ra0.z = pk2(f1.x, f1.y); ra0.w = pk2(f1.z, f1.w);
            ra1.x = pk2(f2.x, f2.y); ra1.y = pk2(f2.z, f2.w);
            ra1.z = pk2(f3.x, f3.y); ra1.w = pk2(f3.z, f3.w);
        }
        if (n0 + arow < N) {
            const uint4* pb = reinterpret_cast<const uint4*>(
                Bw + (size_t)(n0 + arow) * K + kb);
            rb0 = pb[0]; rb1 = pb[1];
        } else {
            rb0 = make_uint4(0, 0, 0, 0); rb1 = rb0;
        }
    };
    auto lwrite = [&](int buf) {
        *reinterpret_cast<uint4*>(&As[buf][wA])     = ra0;
        *reinterpret_cast<uint4*>(&As[buf][wA + 8]) = ra1;
        *reinterpret_cast<uint4*>(&Bs[buf][wA])     = rb0;
        *reinterpret_cast<uint4*>(&Bs[buf][wA + 8]) = rb1;
    };

    const int KI = K >> 5;
    loadg(0);
    lwrite(0);
    __syncthreads();

    int buf = 0;
    for (int kk = 0; kk < KI; ++kk) {
        const bool more = (kk + 1) < KI;
        if (more) loadg(kk + 1);
        bf16x8 af[4], bfr[4];
#pragma unroll
        for (int mi = 0; mi < 4; ++mi)
            af[mi] = *reinterpret_cast<const bf16x8*>(&As[buf][rA0 + mi * 16 * 40]);
#pragma unroll
        for (int ni = 0; ni < 4; ++ni)
            bfr[ni] = *reinterpret_cast<const bf16x8*>(&Bs[buf][rB0 + ni * 16 * 40]);
#pragma unroll
        for (int mi = 0; mi < 4; ++mi)
#pragma unroll
            for (int ni = 0; ni < 4; ++ni)
                acc[mi][ni] = __builtin_amdgcn_mfma_f32_16x16x32_bf16(
                    af[mi], bfr[ni], acc[mi][ni], 0, 0, 0);
        if (more) lwrite(buf ^ 1);
        __syncthreads();
        buf ^= 1;
    }

    const int mB = m0 + wy * 64 + (lane >> 4) * 4;
    const int nB = n0 + wx * 64 + lm;
#pragma unroll
    for (int mi = 0; mi < 4; ++mi) {
#pragma unroll
        for (int ni = 0; ni < 4; ++ni) {
            const int n = nB + ni * 16;
            if (EPI == 2) {                              // transposed float4
                const int mrow = mB + mi * 16;
                const int bb = mrow >> 12, l = mrow & 4095;
                float4 st = {acc[mi][ni][0], acc[mi][ni][1],
                             acc[mi][ni][2], acc[mi][ni][3]};
                *reinterpret_cast<float4*>(
                    C + ((size_t)(bb * CDIM + n)) * SDIM + l) = st;
            } else {
#pragma unroll
                for (int j = 0; j < 4; ++j) {
                    const int m = mB + mi * 16 + j;
                    const float v = acc[mi][ni][j];
                    if (EPI == 0) {
                        if (n < N) C[(size_t)m * ldc + n] = v;
                    } else {                             // xz split
                        if (n < DINC) C[(size_t)m * DINC + n] = v;
                        else          C2[(size_t)m * DINC + (n - DINC)] = v;
                    }
                }
            }
        }
    }
}

// ---------------------------------------------------------------------------
// InstanceNorm stats, single input: one block per (b,c).
// ---------------------------------------------------------------------------
__global__ __launch_bounds__(256)
void inorm_stats_kernel(const float* __restrict__ X, float* __restrict__ stats) {
    const int bc = blockIdx.x;
    const float* xp = X + (size_t)bc * SDIM;
    float s = 0.f, ss = 0.f;
    for (int i = threadIdx.x * 4; i < SDIM; i += 1024) {
        float4 v = *(const float4*)(xp + i);
        s += v.x + v.y + v.z + v.w;
        ss += v.x * v.x + v.y * v.y + v.z * v.z + v.w * v.w;
    }
#pragma unroll
    for (int off = 32; off > 0; off >>= 1) {
        s += __shfl_down(s, off);
        ss += __shfl_down(ss, off);
    }
    __shared__ float rs[4], rss[4];
    const int wid = threadIdx.x >> 6;
    if ((threadIdx.x & 63) == 0) { rs[wid] = s; rss[wid] = ss; }
    __syncthreads();
    if (threadIdx.x == 0) {
        float S = rs[0] + rs[1] + rs[2] + rs[3];
        float SS = rss[0] + rss[1] + rss[2] + rss[3];
        float m = S * (1.f / SDIM);
        float var = SS * (1.f / SDIM) - m * m;
        stats[bc * 2] = m;
        stats[bc * 2 + 1] = rsqrtf(var + 1e-5f);
    }
}

// ---------------------------------------------------------------------------
// InstanceNorm stats over the SUM of two partials.
// ---------------------------------------------------------------------------
__global__ __launch_bounds__(256)
void inorm_stats2_kernel(const float* __restrict__ P0, const float* __restrict__ P1,
                         float* __restrict__ stats) {
    const int bc = blockIdx.x;
    const float* p0 = P0 + (size_t)bc * SDIM;
    const float* p1 = P1 + (size_t)bc * SDIM;
    float s = 0.f, ss = 0.f;
    for (int i = threadIdx.x * 4; i < SDIM; i += 1024) {
        float4 a = *(const float4*)(p0 + i);
        float4 c = *(const float4*)(p1 + i);
        const float vx = a.x + c.x, vy = a.y + c.y, vz = a.z + c.z, vw = a.w + c.w;
        s += vx + vy + vz + vw;
        ss += vx * vx + vy * vy + vz * vz + vw * vw;
    }
#pragma unroll
    for (int off = 32; off > 0; off >>= 1) {
        s += __shfl_down(s, off);
        ss += __shfl_down(ss, off);
    }
    __shared__ float rs[4], rss[4];
    const int wid = threadIdx.x >> 6;
    if ((threadIdx.x & 63) == 0) { rs[wid] = s; rss[wid] = ss; }
    __syncthreads();
    if (threadIdx.x == 0) {
        float S = rs[0] + rs[1] + rs[2] + rs[3];
        float SS = rss[0] + rss[1] + rss[2] + rss[3];
        float m = S * (1.f / SDIM);
        float var = SS * (1.f / SDIM) - m * m;
        stats[bc * 2] = m;
        stats[bc * 2 + 1] = rsqrtf(var + 1e-5f);
    }
}

// ---------------------------------------------------------------------------
// Fused LayerNorm: xg = relu((C4-m)*r) + x computed inline, then LN over C
// with transpose: -> tn [b][l][c] bf16.
// ---------------------------------------------------------------------------
__global__ __launch_bounds__(256)
void layernorm_kernel(const float* __restrict__ C4, const float* __restrict__ stats,
                      const float* __restrict__ X, const float* __restrict__ gam,
                      const float* __restrict__ bet, ushort_t* __restrict__ Tn) {
    const int token = blockIdx.x * 4 + (threadIdx.x >> 6);
    const int lane = threadIdx.x & 63;
    const int b = token >> 12, l = token & 4095;
    const size_t base = (size_t)b * CDIM * SDIM + l;
    float v[6];
    float s = 0.f, ss = 0.f;
#pragma unroll
    for (int i = 0; i < 6; ++i) {
        const int c = lane + i * 64;
        const size_t o = base + (size_t)c * SDIM;
        const float m = stats[(b * CDIM + c) * 2], r = stats[(b * CDIM + c) * 2 + 1];
        v[i] = fmaxf((C4[o] - m) * r, 0.f) + X[o];
        s += v[i]; ss += v[i] * v[i];
    }
#pragma unroll
    for (int off = 32; off > 0; off >>= 1) {
        s += __shfl_down(s, off);
        ss += __shfl_down(ss, off);
    }
    s = __shfl(s, 0); ss = __shfl(ss, 0);
    const float m = s * (1.f / CDIM);
    const float r = rsqrtf(ss * (1.f / CDIM) - m * m + 1e-5f);
    ushort_t* tp = Tn + (size_t)token * CDIM;
#pragma unroll
    for (int i = 0; i < 6; ++i) {
        const int c = lane + i * 64;
        tp[c] = f2bf((v[i] - m) * r * gam[c] + bet[c]);
    }
}

// ---------------------------------------------------------------------------
// Tiled fp32 GEMM for dt_proj (K=24), NT, bias+softplus epilogue.
// ---------------------------------------------------------------------------
__global__ __launch_bounds__(256)
void gemm_dtproj_kernel(const float* __restrict__ A, const float* __restrict__ B,
                        float* __restrict__ C, const float* __restrict__ bias,
                        int M, int N, int K, int lda, int ldb, int ldc) {
    __shared__ __align__(16) float As[16][132];
    __shared__ __align__(16) float Bs[16][68];
    const int t = threadIdx.x;
    const int m0 = blockIdx.y * 128;
    const int n0 = blockIdx.x * 64;

    float acc[8][4];
#pragma unroll
    for (int i = 0; i < 8; ++i)
#pragma unroll
        for (int j = 0; j < 4; ++j) acc[i][j] = 0.f;

    const int mr = (t & 15) * 8;
    const int nr = (t >> 4) * 4;

    for (int k0 = 0; k0 < K; k0 += 16) {
#pragma unroll
        for (int idx = 0; idx < 8; ++idx) {
            const int e = idx * 256 + t;
            const int k = e & 15, m = e >> 4;
            float v = 0.f;
            if (k0 + k < K) v = A[(size_t)(m0 + m) * lda + (k0 + k)];
            As[k][m] = v;
        }
#pragma unroll
        for (int idx = 0; idx < 4; ++idx) {
            const int e = idx * 256 + t;
            const int k = e & 15, n = e >> 4;
            float v = 0.f;
            if ((n0 + n) < N && (k0 + k) < K) v = B[(size_t)(n0 + n) * ldb + (k0 + k)];
            Bs[k][n] = v;
        }
        __syncthreads();
#pragma unroll
        for (int k = 0; k < 16; ++k) {
            float4 a0 = *(const float4*)&As[k][mr];
            float4 a1 = *(const float4*)&As[k][mr + 4];
            float4 b0 = *(const float4*)&Bs[k][nr];
            const float av[8] = {a0.x, a0.y, a0.z, a0.w, a1.x, a1.y, a1.z, a1.w};
            const float bv[4] = {b0.x, b0.y, b0.z, b0.w};
#pragma unroll
            for (int i = 0; i < 8; ++i)
#pragma unroll
                for (int j = 0; j < 4; ++j)
                    acc[i][j] = fmaf(av[i], bv[j], acc[i][j]);
        }
        __syncthreads();
    }

#pragma unroll
    for (int i = 0; i < 8; ++i) {
        const int m = m0 + mr + i;
#pragma unroll
        for (int j = 0; j < 4; ++j) {
            const int n = n0 + nr + j;
            if (n >= N) continue;
            float v = acc[i][j] + bias[n];
            v = (v > 20.f) ? v : log1pf(__expf(v));
            C[(size_t)m * ldc + n] = v;
        }
    }
}

// ---------------------------------------------------------------------------
// Causal depthwise conv1d (K=4) + bias + SiLU.
// ---------------------------------------------------------------------------
__global__ __launch_bounds__(256)
void dwconv_silu_kernel(const float* __restrict__ Xin, const float* __restrict__ W,
                        const float* __restrict__ bias, float* __restrict__ U) {
    const int dch = blockIdx.x * 256 + threadIdx.x;
    const int l = blockIdx.y, b = blockIdx.z;
    const float4 w4 = ((const float4*)W)[dch];
    const float wk[4] = {w4.x, w4.y, w4.z, w4.w};
    const float* xp = Xin + ((size_t)b * 4096 + l) * DINC + dch;
    float acc = bias[dch];
#pragma unroll
    for (int k = 0; k < 4; ++k) {
        const int ll = l - 3 + k;
        if (ll >= 0) acc = fmaf(xp[(k - 3) * DINC], wk[k], acc);
    }
    U[((size_t)b * 4096 + l) * DINC + dch] = acc / (1.f + __expf(-acc));
}

// ---------------------------------------------------------------------------
// Chunked parallel selective scan (3 phases), unchanged.
// ---------------------------------------------------------------------------
__global__ __launch_bounds__(256)
void scan_phase1_kernel(const float* __restrict__ DT, const float* __restrict__ U,
                        const float* __restrict__ DBL, const float* __restrict__ A_log,
                        float* __restrict__ HOUT, float* __restrict__ SDT) {
    const int b = blockIdx.z, chunk = blockIdx.y;
    const int dch = blockIdx.x * 256 + threadIdx.x;
    float Arow[16];
#pragma unroll
    for (int n = 0; n < NST; ++n) Arow[n] = -__expf(A_log[dch * NST + n]);

    __shared__ float bcs[LCHUNK][16];
    const size_t tokbase = (size_t)b * 4096 + chunk * LCHUNK;
#pragma unroll
    for (int idx = 0; idx < 4; ++idx) {
        const int e = idx * 256 + threadIdx.x;
        bcs[e >> 4][e & 15] = DBL[(tokbase + (e >> 4)) * 56 + 24 + (e & 15)];
    }
    __syncthreads();

    size_t off = tokbase * DINC + dch;
    float h[16];
#pragma unroll
    for (int n = 0; n < NST; ++n) h[n] = 0.f;
    float sdt = 0.f;
    float cdt = DT[off], cu = U[off];
    for (int t = 0; t < LCHUNK; ++t) {
        float ndt = 0.f, nu = 0.f;
        if (t < LCHUNK - 1) { ndt = DT[off + DINC]; nu = U[off + DINC]; }
        sdt += cdt;
        const float du = cdt * cu;
#pragma unroll
        for (int n = 0; n < NST; ++n)
            h[n] = __expf(cdt * Arow[n]) * h[n] + du * bcs[t][n];
        off += DINC;
        cdt = ndt; cu = nu;
    }
    float* hp = HOUT + (((size_t)(b * DINC + dch) * NCHUNK + chunk) << 4);
#pragma unroll
    for (int n = 0; n < NST; ++n) hp[n] = h[n];
    SDT[(size_t)(b * DINC + dch) * NCHUNK + chunk] = sdt;
}

__global__ __launch_bounds__(256)
void scan_phase2_kernel(float* __restrict__ HOUT, const float* __restrict__ SDT,
                        const float* __restrict__ A_log) {
    const int t = blockIdx.x * 256 + threadIdx.x;        // 49152
    const int b = t / (DINC * NST);
    const int rem = t - b * (DINC * NST);
    const int d = rem >> 4, n = rem & 15;
    const float An = -__expf(A_log[d * NST + n]);
    float* hp = HOUT + (((size_t)(b * DINC + d) * NCHUNK) << 4) + n;
    const float* sp = SDT + (size_t)(b * DINC + d) * NCHUNK;
    float H = 0.f;
    for (int c = 0; c < NCHUNK; ++c) {
        const float tmp = hp[c * 16];
        const float dA = __expf(An * sp[c]);
        hp[c * 16] = H;
        H = dA * H + tmp;
    }
}

__global__ __launch_bounds__(256)
void scan_phase3_kernel(float* __restrict__ DT, const float* __restrict__ U,
                        const float* __restrict__ DBL, const float* __restrict__ Z,
                        const float* __restrict__ A_log, const float* __restrict__ D_skip,
                        const float* __restrict__ HOUT) {
    const int b = blockIdx.z, chunk = blockIdx.y;
    const int dch = blockIdx.x * 256 + threadIdx.x;
    float Arow[16];
#pragma unroll
    for (int n = 0; n < NST; ++n) Arow[n] = -__expf(A_log[dch * NST + n]);
    const float Dsk = D_skip[dch];

    __shared__ float bcs[LCHUNK][32];
    const size_t tokbase = (size_t)b * 4096 + chunk * LCHUNK;
#pragma unroll
    for (int idx = 0; idx < 8; ++idx) {
        const int e = idx * 256 + threadIdx.x;
        bcs[e >> 5][e & 31] = DBL[(tokbase + (e >> 5)) * 56 + 24 + (e & 31)];
    }
    __syncthreads();

    float h[16];
    const float* hp = HOUT + (((size_t)(b * DINC + dch) * NCHUNK + chunk) << 4);
#pragma unroll
    for (int n = 0; n < NST; ++n) h[n] = hp[n];

    size_t off = tokbase * DINC + dch;
    float cdt = DT[off], cu = U[off], cz = Z[off];
    for (int t = 0; t < LCHUNK; ++t) {
        float ndt = 0.f, nu = 0.f, nz = 0.f;
        if (t < LCHUNK - 1) {
            ndt = DT[off + DINC]; nu = U[off + DINC]; nz = Z[off + DINC];
        }
        const float du = cdt * cu;
        float y = 0.f;
#pragma unroll
        for (int n = 0; n < NST; ++n) {
            h[n] = __expf(cdt * Arow[n]) * h[n] + du * bcs[t][n];
            y = fmaf(h[n], bcs[t][16 + n], y);
        }
        y += cu * Dsk;
        const float sz = cz / (1.f + __expf(-cz));
        DT[off] = y * sz;
        off += DINC;
        cdt = ndt; cu = nu; cz = nz;
    }
}

// ---------------------------------------------------------------------------
extern "C" void kernel_launch(void* const* d_in, const int* in_sizes, int n_in,
                              void* d_out, int out_size, void* d_ws, size_t ws_size,
                              hipStream_t stream) {
    (void)in_sizes; (void)n_in; (void)out_size; (void)ws_size;
    const float* x         = (const float*)d_in[0];
    const float* w1        = (const float*)d_in[1];
    const float* w2        = (const float*)d_in[3];
    const float* w3        = (const float*)d_in[5];
    const float* w4        = (const float*)d_in[7];
    const float* ln_g      = (const float*)d_in[9];
    const float* ln_b      = (const float*)d_in[10];
    const float* in_proj_w = (const float*)d_in[11];
    const float* conv1d_w  = (const float*)d_in[12];
    const float* conv1d_b  = (const float*)d_in[13];
    const float* x_proj_w  = (const float*)d_in[14];
    const float* dt_proj_w = (const float*)d_in[15];
    const float* dt_proj_b = (const float*)d_in[16];
    const float* A_log     = (const float*)d_in[17];
    const float* D_skip    = (const float*)d_in[18];
    const float* out_proj_w= (const float*)d_in[19];
    float* out = (float*)d_out;

    // Workspace regions (floats): R0..R4. Lifetimes disjoint where aliased.
    float* ws = (float*)d_ws;
    float* R0 = ws;                    //  6291456
    float* R1 = ws + 6291456;          //  6291456
    float* R2 = ws + 12582912;         // 12582912
    float* R3 = ws + 25165824;         // 12582912
    float* R4 = ws + 37748736;         // 12582912

    // GSC-phase aliases
    float*    P0    = R0;                            // conv partial z=0 (25MB)
    float*    P1    = R1;                            // conv partial z=1 (P0+PSTRIDE)
    ushort_t* Wb27  = (ushort_t*)R2;                 // 3981312 bf16
    ushort_t* Xp    = (ushort_t*)(R2 + 2097152);     // 8957952 bf16
    ushort_t* w3b   = (ushort_t*)(R2 + 6576128);     // 147456 bf16
    ushort_t* w4b   = (ushort_t*)(R2 + 6649856);     // 147456 bf16
    float*    SA    = R4;                            // stats A (3072 fl)
    float*    SB    = R4 + 4096;                     // stats B (3072 fl)
    // Mamba-phase aliases
    ushort_t* tnb   = (ushort_t*)R0;                 // 16384*384 bf16 (3.1M fl)
    float*    DBL   = R0 + 3145728;                  // 16384*56
    ushort_t* ipwb  = (ushort_t*)R1;                 // 1536*384 bf16
    ushort_t* opwb  = (ushort_t*)(R1 + 294912);      // 384*768 bf16
    ushort_t* xpwb  = (ushort_t*)(R1 + 442368);      // 56*768 bf16
    float*    HOUT  = R1 + 463872;                   // 3145728
    float*    SDT   = R1 + 3609600;                  // 196608
    float*    XIN   = R2;                            // 16384*768 (over Wb/Xp)
    float*    Zb    = R3;                            // 16384*768
    float*    Ub    = R4;                            // 16384*768
    float*    DTb   = R2;                            // dt/y over XIN

    const size_t XP_BYTES = (size_t)4 * 18 * 18 * 18 * CDIM * 2;
    const dim3 cgrid27(128, 3, 2);
    const dim3 cgrid1(128, 3, 1);

    // ---- GSC block ----
    hipMemsetAsync(Xp, 0, XP_BYTES, stream);             // zero pad borders
    pad_kernel<<<1024, 384, 0, stream>>>(x, Xp);         // x channels-last
    wconv_kernel<<<576, 256, 0, stream>>>(w1, Wb27);
    cvt_bf16_kernel<<<144, 256, 0, stream>>>(w3, w3b, 36864);
    cvt_bf16_kernel<<<144, 256, 0, stream>>>(w4, w4b, 36864);
    conv_mfma_kernel<27, 2><<<cgrid27, 256, 0, stream>>>(Xp, Wb27, P0);   // c1
    conv_mfma_kernel<1, 1><<<cgrid1, 256, 0, stream>>>(Xp, w3b, R3);      // c3
    inorm_stats2_kernel<<<1536, 256, 0, stream>>>(P0, P1, SA);
    pad_fuse2_kernel<<<1024, 384, 0, stream>>>(P0, P1, SA, Xp);           // x1a
    wconv_kernel<<<576, 256, 0, stream>>>(w2, Wb27);
    conv_mfma_kernel<27, 2><<<cgrid27, 256, 0, stream>>>(Xp, Wb27, P0);   // c2
    inorm_stats2_kernel<<<1536, 256, 0, stream>>>(P0, P1, SA);            // c2 stats
    inorm_stats_kernel<<<1536, 256, 0, stream>>>(R3, SB);                 // c3 stats
    pad_fuse3_kernel<<<1024, 384, 0, stream>>>(P0, P1, SA, R3, SB, Xp);   // S
    conv_mfma_kernel<1, 1><<<cgrid1, 256, 0, stream>>>(Xp, w4b, R3);      // c4
    inorm_stats_kernel<<<1536, 256, 0, stream>>>(R3, SA);                 // c4 stats
    // ---- fused relu(IN(c4)) + x residual + LayerNorm -> tn bf16 [b][l][c]
    layernorm_kernel<<<4096, 256, 0, stream>>>(R3, SA, x, ln_g, ln_b, tnb);
    // ---- weight converts (R1 free now)
    cvt_bf16_kernel<<<576, 256, 0, stream>>>(in_proj_w, ipwb, 147456);
    cvt_bf16_kernel<<<288, 256, 0, stream>>>(out_proj_w, opwb, 73728);
    cvt_bf16_kernel<<<42, 256, 0, stream>>>(x_proj_w, xpwb, 10752);
    // ---- in_proj (bf16 MFMA): tn x W^T -> split XIN | Zb
    gemm_mfma_kernel<ushort_t, 1><<<dim3(12, 128), 256, 0, stream>>>(
        tnb, ipwb, XIN, Zb, 16384, 1536, CDIM, 0);
    // ---- causal depthwise conv + SiLU -> Ub
    dwconv_silu_kernel<<<dim3(3, 4096, 4), 256, 0, stream>>>(XIN, conv1d_w, conv1d_b, Ub);
    // ---- x_proj (bf16 MFMA, N=56 masked): u x W^T -> DBL
    gemm_mfma_kernel<float, 0><<<dim3(1, 128), 256, 0, stream>>>(
        Ub, xpwb, DBL, nullptr, 16384, 56, DINC, 56);
    // ---- dt_proj (fp32, K=24) + bias + softplus -> DTb (over XIN)
    gemm_dtproj_kernel<<<dim3(12, 128), 256, 0, stream>>>(
        DBL, dt_proj_w, DTb, dt_proj_b, 16384, DINC, 24, 56, 24, DINC);
    // ---- chunked parallel selective scan (y over DTb, fp32)
    scan_phase1_kernel<<<dim3(3, NCHUNK, 4), 256, 0, stream>>>(
        DTb, Ub, DBL, A_log, HOUT, SDT);
    scan_phase2_kernel<<<192, 256, 0, stream>>>(HOUT, SDT, A_log);
    scan_phase3_kernel<<<dim3(3, NCHUNK, 4), 256, 0, stream>>>(
        DTb, Ub, DBL, Zb, A_log, D_skip, HOUT);
    // ---- out_proj (bf16 MFMA, fp32-A converting loader) -> d_out transposed
    gemm_mfma_kernel<float, 2><<<dim3(3, 128), 256, 0, stream>>>(
        DTb, opwb, out, nullptr, 16384, CDIM, DINC, 0);
}